// Round 3
// baseline (532.871 us; speedup 1.0000x reference)
//
#include <hip/hip_runtime.h>
#include <hip/hip_bf16.h>
#include <stdint.h>

#define HIDDEN 768
#define NH 12
#define HD 64
#define BB 8
#define SS 128
#define LL 16
#define LS 8
#define TT 136            // SS + LS
#define NROWS 1152        // BB*SS + LL*LS rows of the unique-row Xcat
#define T32M 36           // 1152/32 row tiles
#define T32N 72           // 2304/32 col tiles

typedef __attribute__((ext_vector_type(8))) short bf16x8;
typedef __attribute__((ext_vector_type(4))) float f32x4;
typedef __hip_bfloat16 bf16;

__device__ inline float tof(bf16 x) { return __bfloat162float(x); }

// Convert 8 consecutive f32 (16B-aligned) to a bf16x8 MFMA fragment.
__device__ inline bf16x8 cvt8(const float* __restrict__ p) {
    float4 x = reinterpret_cast<const float4*>(p)[0];
    float4 y = reinterpret_cast<const float4*>(p)[1];
    union { bf16 h; short s; } u;
    bf16x8 r;
    u.h = __float2bfloat16(x.x); r[0] = u.s;
    u.h = __float2bfloat16(x.y); r[1] = u.s;
    u.h = __float2bfloat16(x.z); r[2] = u.s;
    u.h = __float2bfloat16(x.w); r[3] = u.s;
    u.h = __float2bfloat16(y.x); r[4] = u.s;
    u.h = __float2bfloat16(y.y); r[5] = u.s;
    u.h = __float2bfloat16(y.z); r[6] = u.s;
    u.h = __float2bfloat16(y.w); r[7] = u.s;
    return r;
}

// ---------------------------------------------------------------------------
// QKV projection over the 1152 UNIQUE rows (1024 token + 128 label):
// C[1152,2304] = Xcat @ [Wq;Wk;Wv]^T + bias.  One wave = one 32x32 output
// tile = 2x2 MFMA 16x16x32 sub-tiles. f32 sources converted to bf16 frags
// in-register. A frag: m=lane&15, k=quad*8+j; B frag from W[out,in] rows
// (natively B^T layout); C/D: col=lane&15, row=quad*4+reg.
// ---------------------------------------------------------------------------
__global__ __launch_bounds__(256) void qkv_kernel(
    const float* __restrict__ tok, const float* __restrict__ lab,
    const float* __restrict__ Wq, const float* __restrict__ bq,
    const float* __restrict__ Wk, const float* __restrict__ bk,
    const float* __restrict__ Wv, const float* __restrict__ bv,
    bf16* __restrict__ Qw, bf16* __restrict__ Kw, bf16* __restrict__ Vw)
{
    int wv = threadIdx.x >> 6, lane = threadIdx.x & 63;
    int w = blockIdx.x * 4 + wv;                   // 0..2591
    int tn = w % T32N, tm = w / T32N;
    int ml = lane & 15, quad = lane >> 4;

    // A rows (32-row tile never straddles the 1024 boundary: 1024 = 32*32)
    int r0 = tm * 32 + ml;
    const float* abase = (r0 < 1024) ? tok : (lab - 1024 * HIDDEN);
    const float* arow0 = abase + (size_t)r0 * HIDDEN;
    const float* arow1 = arow0 + 16 * HIDDEN;

    // B rows = weight output-cols (32-col tile never straddles Q/K/V: 768%32==0)
    int n0 = tn * 32 + ml;                         // [0,2304)
    int mat = n0 / HIDDEN;                         // 0=Q 1=K 2=V, tile-uniform
    int col0 = n0 - mat * HIDDEN;
    const float* wbase = (mat == 0) ? Wq : ((mat == 1) ? Wk : Wv);
    const float* brow0 = wbase + (size_t)col0 * HIDDEN;
    const float* brow1 = brow0 + 16 * HIDDEN;

    f32x4 acc00 = {0,0,0,0}, acc01 = {0,0,0,0}, acc10 = {0,0,0,0}, acc11 = {0,0,0,0};
    #pragma unroll 2
    for (int k0 = 0; k0 < HIDDEN; k0 += 32) {
        int ko = k0 + quad * 8;
        bf16x8 a0 = cvt8(arow0 + ko);
        bf16x8 a1 = cvt8(arow1 + ko);
        bf16x8 b0 = cvt8(brow0 + ko);
        bf16x8 b1 = cvt8(brow1 + ko);
        acc00 = __builtin_amdgcn_mfma_f32_16x16x32_bf16(a0, b0, acc00, 0, 0, 0);
        acc01 = __builtin_amdgcn_mfma_f32_16x16x32_bf16(a0, b1, acc01, 0, 0, 0);
        acc10 = __builtin_amdgcn_mfma_f32_16x16x32_bf16(a1, b0, acc10, 0, 0, 0);
        acc11 = __builtin_amdgcn_mfma_f32_16x16x32_bf16(a1, b1, acc11, 0, 0, 0);
    }

    const float* bptr = (mat == 0) ? bq : ((mat == 1) ? bk : bv);
    int cq0 = tn * 32 + ml - mat * HIDDEN;         // = col0
    int cq1 = cq0 + 16;
    float bv0 = bptr[cq0], bv1 = bptr[cq1];
    bf16* obase = (mat == 0) ? Qw : ((mat == 1) ? Kw : Vw);

    #pragma unroll
    for (int reg = 0; reg < 4; ++reg) {
        int row0 = tm * 32 + quad * 4 + reg;       // C/D row = quad*4+reg
        int row1 = row0 + 16;
        obase[(size_t)row0 * HIDDEN + cq0] = __float2bfloat16(acc00[reg] + bv0);
        obase[(size_t)row0 * HIDDEN + cq1] = __float2bfloat16(acc01[reg] + bv1);
        obase[(size_t)row1 * HIDDEN + cq0] = __float2bfloat16(acc10[reg] + bv0);
        obase[(size_t)row1 * HIDDEN + cq1] = __float2bfloat16(acc11[reg] + bv1);
    }
}

// ---------------------------------------------------------------------------
// Attention: one block per (b,l,h). All 136 K/V rows for this head staged in
// LDS (bf16x2 words, row stride 33 to dodge bank conflicts). 4 waves x 34
// query rows each: full softmax (all keys resident), then PV (lane = dim).
// Masks read as f32 from d_in; output stored f32.
// ---------------------------------------------------------------------------
__global__ __launch_bounds__(256) void attn_kernel(
    const bf16* __restrict__ Qw, const bf16* __restrict__ Kw,
    const bf16* __restrict__ Vw,
    const float* __restrict__ tmask, const float* __restrict__ lmask,
    float* __restrict__ out)
{
    __shared__ uint32_t ks[TT * 33];   // 136 rows x 32 bf16x2 words (+1 pad)
    __shared__ uint32_t vs[TT * 33];
    __shared__ float qs[4][64];
    __shared__ float ef[4][TT];
    __shared__ float bias_s[TT];

    int h = blockIdx.x % NH;
    int l = (blockIdx.x / NH) % LL;
    int b = blockIdx.x / (NH * LL);
    int tid = threadIdx.x;
    int lane = tid & 63, wv = tid >> 6;

    // stage K/V head-slices (bf16 pairs = u32 words)
    for (int i = tid; i < TT * 32; i += 256) {
        int s = i >> 5, w = i & 31;
        int row = (s < SS) ? (b * SS + s) : (1024 + l * LS + (s - SS));
        const uint32_t* kp = reinterpret_cast<const uint32_t*>(Kw + (size_t)row * HIDDEN + h * HD);
        const uint32_t* vp = reinterpret_cast<const uint32_t*>(Vw + (size_t)row * HIDDEN + h * HD);
        ks[s * 33 + w] = kp[w];
        vs[s * 33 + w] = vp[w];
    }
    for (int i = tid; i < TT; i += 256) {
        float mm = (i < SS) ? tmask[b * SS + i] : lmask[l * LS + (i - SS)];
        bias_s[i] = (1.0f - mm) * -10000.0f;
    }
    __syncthreads();

    for (int ti = 0; ti < 34; ++ti) {
        int t = wv * 34 + ti;
        int row_q = (t < SS) ? (b * SS + t) : (1024 + l * LS + (t - SS));
        qs[wv][lane] = tof(Qw[(size_t)row_q * HIDDEN + h * HD + lane]);
        const float2* qp = reinterpret_cast<const float2*>(&qs[wv][0]);

        // scores: lane handles keys {lane, lane+64, lane+128 (lanes 0..7)}
        float scj[3];
        float lmax = -1e30f;
        int nk = (lane < (TT - 128)) ? 3 : 2;
        for (int j = 0; j < nk; ++j) {
            int s = lane + 64 * j;
            float acc = 0.f;
            #pragma unroll
            for (int d2 = 0; d2 < 32; ++d2) {
                uint32_t kw = ks[s * 33 + d2];
                float kx = __uint_as_float((kw & 0xffffu) << 16);
                float ky = __uint_as_float(kw & 0xffff0000u);
                float2 qf = qp[d2];
                acc = fmaf(qf.x, kx, acc);
                acc = fmaf(qf.y, ky, acc);
            }
            float v = acc * 0.125f + bias_s[s];
            scj[j] = v;
            lmax = fmaxf(lmax, v);
        }
        float m = lmax;
        #pragma unroll
        for (int off = 32; off > 0; off >>= 1) m = fmaxf(m, __shfl_xor(m, off));
        float Z = 0.f;
        for (int j = 0; j < nk; ++j) {
            float e = __expf(scj[j] - m);
            ef[wv][lane + 64 * j] = e;
            Z += e;
        }
        #pragma unroll
        for (int off = 32; off > 0; off >>= 1) Z += __shfl_xor(Z, off);

        // ctx: lane = head dim d (pairs of lanes share one V word: free 2-way)
        float acc = 0.f;
        int d2v = lane >> 1;
        bool hi = (lane & 1) != 0;
        for (int s = 0; s < TT; ++s) {
            uint32_t vw = vs[s * 33 + d2v];
            float vvf = hi ? __uint_as_float(vw & 0xffff0000u)
                           : __uint_as_float((vw & 0xffffu) << 16);
            acc = fmaf(ef[wv][s], vvf, acc);
        }
        float ctx = acc / Z;
        // fused[b, t, l, h*64 + d]
        out[(((size_t)b * TT + t) * LL + l) * HIDDEN + h * HD + lane] = ctx;
    }
}

extern "C" void kernel_launch(void* const* d_in, const int* in_sizes, int n_in,
                              void* d_out, int out_size, void* d_ws, size_t ws_size,
                              hipStream_t stream)
{
    const float* tok   = (const float*)d_in[0];
    const float* lab   = (const float*)d_in[1];
    const float* tmask = (const float*)d_in[2];
    const float* lmask = (const float*)d_in[3];
    const float* Wq    = (const float*)d_in[4];
    const float* bq    = (const float*)d_in[5];
    const float* Wk    = (const float*)d_in[6];
    const float* bk    = (const float*)d_in[7];
    const float* Wv    = (const float*)d_in[8];
    const float* bv    = (const float*)d_in[9];

    // ws: bf16 Q/K/V only — 3 * 1152*768*2 B = 5,308,416 B total.
    bf16* Qw = (bf16*)d_ws;
    bf16* Kw = Qw + (size_t)NROWS * HIDDEN;
    bf16* Vw = Kw + (size_t)NROWS * HIDDEN;

    qkv_kernel<<<dim3(T32M * T32N / 4), 256, 0, stream>>>(
        tok, lab, Wq, bq, Wk, bk, Wv, bv, Qw, Kw, Vw);
    attn_kernel<<<dim3(BB * LL * NH), 256, 0, stream>>>(
        Qw, Kw, Vw, tmask, lmask, (float*)d_out);
}

// Round 4
// 273.775 us; speedup vs baseline: 1.9464x; 1.9464x over previous
//
#include <hip/hip_runtime.h>
#include <hip/hip_bf16.h>
#include <stdint.h>

#define HIDDEN 768
#define NH 12
#define HD 64
#define BB 8
#define SS 128
#define LL 16
#define LS 8
#define TT 136            // SS + LS
#define NROWS 1152        // BB*SS + LL*LS rows of the unique-row Xcat
#define T32M 36           // 1152/32 row tiles
#define T32N 72           // 2304/32 col tiles

typedef __attribute__((ext_vector_type(8))) short bf16x8;
typedef __attribute__((ext_vector_type(4))) float f32x4;
typedef __hip_bfloat16 bf16;

__device__ inline float tof(bf16 x) { return __bfloat162float(x); }
__device__ inline uint16_t b16bits(float f) {
    bf16 h = __float2bfloat16(f);
    union { bf16 h; uint16_t u; } u; u.h = h; return u.u;
}

// Convert 8 consecutive f32 (16B-aligned) to a bf16x8 MFMA fragment.
__device__ inline bf16x8 cvt8(const float* __restrict__ p) {
    float4 x = reinterpret_cast<const float4*>(p)[0];
    float4 y = reinterpret_cast<const float4*>(p)[1];
    union { bf16 h; short s; } u;
    bf16x8 r;
    u.h = __float2bfloat16(x.x); r[0] = u.s;
    u.h = __float2bfloat16(x.y); r[1] = u.s;
    u.h = __float2bfloat16(x.z); r[2] = u.s;
    u.h = __float2bfloat16(x.w); r[3] = u.s;
    u.h = __float2bfloat16(y.x); r[4] = u.s;
    u.h = __float2bfloat16(y.y); r[5] = u.s;
    u.h = __float2bfloat16(y.z); r[6] = u.s;
    u.h = __float2bfloat16(y.w); r[7] = u.s;
    return r;
}

// ---------------------------------------------------------------------------
// QKV projection (unchanged from round 3 — passing; optimize next round).
// ---------------------------------------------------------------------------
__global__ __launch_bounds__(256) void qkv_kernel(
    const float* __restrict__ tok, const float* __restrict__ lab,
    const float* __restrict__ Wq, const float* __restrict__ bq,
    const float* __restrict__ Wk, const float* __restrict__ bk,
    const float* __restrict__ Wv, const float* __restrict__ bv,
    bf16* __restrict__ Qw, bf16* __restrict__ Kw, bf16* __restrict__ Vw)
{
    int wv = threadIdx.x >> 6, lane = threadIdx.x & 63;
    int w = blockIdx.x * 4 + wv;                   // 0..2591
    int tn = w % T32N, tm = w / T32N;
    int ml = lane & 15, quad = lane >> 4;

    int r0 = tm * 32 + ml;
    const float* abase = (r0 < 1024) ? tok : (lab - 1024 * HIDDEN);
    const float* arow0 = abase + (size_t)r0 * HIDDEN;
    const float* arow1 = arow0 + 16 * HIDDEN;

    int n0 = tn * 32 + ml;                         // [0,2304)
    int mat = n0 / HIDDEN;                         // 0=Q 1=K 2=V, tile-uniform
    int col0 = n0 - mat * HIDDEN;
    const float* wbase = (mat == 0) ? Wq : ((mat == 1) ? Wk : Wv);
    const float* brow0 = wbase + (size_t)col0 * HIDDEN;
    const float* brow1 = brow0 + 16 * HIDDEN;

    f32x4 acc00 = {0,0,0,0}, acc01 = {0,0,0,0}, acc10 = {0,0,0,0}, acc11 = {0,0,0,0};
    #pragma unroll 2
    for (int k0 = 0; k0 < HIDDEN; k0 += 32) {
        int ko = k0 + quad * 8;
        bf16x8 a0 = cvt8(arow0 + ko);
        bf16x8 a1 = cvt8(arow1 + ko);
        bf16x8 b0 = cvt8(brow0 + ko);
        bf16x8 b1 = cvt8(brow1 + ko);
        acc00 = __builtin_amdgcn_mfma_f32_16x16x32_bf16(a0, b0, acc00, 0, 0, 0);
        acc01 = __builtin_amdgcn_mfma_f32_16x16x32_bf16(a0, b1, acc01, 0, 0, 0);
        acc10 = __builtin_amdgcn_mfma_f32_16x16x32_bf16(a1, b0, acc10, 0, 0, 0);
        acc11 = __builtin_amdgcn_mfma_f32_16x16x32_bf16(a1, b1, acc11, 0, 0, 0);
    }

    const float* bptr = (mat == 0) ? bq : ((mat == 1) ? bk : bv);
    int cq0 = col0, cq1 = col0 + 16;
    float bv0 = bptr[cq0], bv1 = bptr[cq1];
    bf16* obase = (mat == 0) ? Qw : ((mat == 1) ? Kw : Vw);

    #pragma unroll
    for (int reg = 0; reg < 4; ++reg) {
        int row0 = tm * 32 + quad * 4 + reg;       // C/D row = quad*4+reg
        int row1 = row0 + 16;
        obase[(size_t)row0 * HIDDEN + cq0] = __float2bfloat16(acc00[reg] + bv0);
        obase[(size_t)row0 * HIDDEN + cq1] = __float2bfloat16(acc01[reg] + bv1);
        obase[(size_t)row1 * HIDDEN + cq0] = __float2bfloat16(acc10[reg] + bv0);
        obase[(size_t)row1 * HIDDEN + cq1] = __float2bfloat16(acc11[reg] + bv1);
    }
}

// ---------------------------------------------------------------------------
// MFMA attention: one block per (b,l,h), 4 waves. Queries padded to 144
// (9 row-tiles of 16), keys padded to 160 for the PV k-loop.
//  - K staged in LDS [144][72 bf16] (stride 36 words -> 2-way-max aliasing)
//  - V^T built in LDS [64][168 bf16] via coalesced global reads + u32 writes
//  - scores: A=Q frags direct from global, B=K-row frags from LDS
//  - softmax in C-layout regs: cross-lane max/sum over ml (xor 1,2,4,8)
//  - P written to per-wave LDS [16][168 bf16] (u32-packed via shfl), read
//    back as A-frags (same-wave LDS is in-order -> no barrier needed)
//  - PV: A=P, B=V^T; epilogue scales by 1/Z and stores f32
// ---------------------------------------------------------------------------
__global__ __launch_bounds__(256) void attn_kernel(
    const bf16* __restrict__ Qw, const bf16* __restrict__ Kw,
    const bf16* __restrict__ Vw,
    const float* __restrict__ tmask, const float* __restrict__ lmask,
    float* __restrict__ out)
{
    __shared__ __align__(16) uint32_t KldsW[144 * 36];   // 20736 B
    __shared__ __align__(16) uint32_t VtW[64 * 84];      // 21504 B
    __shared__ __align__(16) uint32_t PW[4][16 * 84];    // 21504 B
    __shared__ float bias_s[160];                        //   640 B

    int h = blockIdx.x % NH;
    int l = (blockIdx.x / NH) % LL;
    int b = blockIdx.x / (NH * LL);
    int tid = threadIdx.x;
    int lane = tid & 63, wv = tid >> 6;
    int ml = lane & 15, quad = lane >> 4;

    // --- stage K rows (coalesced u32), zero pad rows 136..143 ---
    for (int i = tid; i < 144 * 32; i += 256) {
        int s = i >> 5, w = i & 31;
        uint32_t val = 0;
        if (s < TT) {
            int row = (s < SS) ? (b * SS + s) : (1024 + l * LS + (s - SS));
            val = reinterpret_cast<const uint32_t*>(Kw + (size_t)row * HIDDEN + h * HD)[w];
        }
        KldsW[s * 36 + w] = val;
    }
    // --- build V^T [d][s] with zero pad s>=136; global reads coalesced ---
    for (int i = tid; i < 64 * 80; i += 256) {
        int d = i & 63, s2 = i >> 6;
        int s0 = 2 * s2, s1 = s0 + 1;
        uint16_t lo = 0, hi = 0;
        if (s0 < TT) {
            int r = (s0 < SS) ? (b * SS + s0) : (1024 + l * LS + (s0 - SS));
            lo = reinterpret_cast<const uint16_t*>(Vw + (size_t)r * HIDDEN + h * HD)[d];
        }
        if (s1 < TT) {
            int r = (s1 < SS) ? (b * SS + s1) : (1024 + l * LS + (s1 - SS));
            hi = reinterpret_cast<const uint16_t*>(Vw + (size_t)r * HIDDEN + h * HD)[d];
        }
        VtW[d * 84 + s2] = (uint32_t)lo | ((uint32_t)hi << 16);
    }
    // --- bias per key col; pad cols get -1e30 so exp -> 0 ---
    for (int i = tid; i < 160; i += 256) {
        float bv;
        if (i < SS)       bv = (1.0f - tmask[b * SS + i]) * -10000.0f;
        else if (i < TT)  bv = (1.0f - lmask[l * LS + (i - SS)]) * -10000.0f;
        else              bv = -1e30f;
        bias_s[i] = bv;
    }
    // --- zero per-wave P pad cols (words 68..79 of each of 16 rows) ---
    for (int i = lane; i < 16 * 12; i += 64) {
        int r = i / 12, w2 = 68 + (i - (i / 12) * 12);
        PW[wv][r * 84 + w2] = 0;
    }
    __syncthreads();

    const bf16* Klb = reinterpret_cast<const bf16*>(KldsW);
    const bf16* Vtb = reinterpret_cast<const bf16*>(VtW);
    const bf16* Pb  = reinterpret_cast<const bf16*>(PW[wv]);

    for (int rt = wv; rt < 9; rt += 4) {
        // Q A-frags direct from global (clamped pad rows; garbage discarded)
        int qr = rt * 16 + ml; if (qr > TT - 1) qr = TT - 1;
        int grow = (qr < SS) ? (b * SS + qr) : (1024 + l * LS + (qr - SS));
        const bf16* qp = Qw + (size_t)grow * HIDDEN + h * HD + quad * 8;
        bf16x8 a0 = *reinterpret_cast<const bf16x8*>(qp);
        bf16x8 a1 = *reinterpret_cast<const bf16x8*>(qp + 32);

        // scores: 9 col-tiles of 16 keys, k=64 in 2 MFMA
        f32x4 sc[9];
        #pragma unroll
        for (int ct = 0; ct < 9; ++ct) {
            const bf16* kp = Klb + (ct * 16 + ml) * 72 + quad * 8;
            bf16x8 b0 = *reinterpret_cast<const bf16x8*>(kp);
            bf16x8 b1 = *reinterpret_cast<const bf16x8*>(kp + 32);
            f32x4 z = {0.f, 0.f, 0.f, 0.f};
            z = __builtin_amdgcn_mfma_f32_16x16x32_bf16(a0, b0, z, 0, 0, 0);
            z = __builtin_amdgcn_mfma_f32_16x16x32_bf16(a1, b1, z, 0, 0, 0);
            sc[ct] = z;
        }

        // scale + bias + row max (rows live on (quad,reg); cols on ml)
        float mx[4] = {-1e30f, -1e30f, -1e30f, -1e30f};
        #pragma unroll
        for (int ct = 0; ct < 9; ++ct) {
            float bc = bias_s[ct * 16 + ml];
            #pragma unroll
            for (int reg = 0; reg < 4; ++reg) {
                float v = sc[ct][reg] * 0.125f + bc;
                sc[ct][reg] = v;
                mx[reg] = fmaxf(mx[reg], v);
            }
        }
        #pragma unroll
        for (int reg = 0; reg < 4; ++reg) {
            #pragma unroll
            for (int off = 1; off < 16; off <<= 1)
                mx[reg] = fmaxf(mx[reg], __shfl_xor(mx[reg], off));
        }
        // exp + row sum
        float Zs[4] = {0.f, 0.f, 0.f, 0.f};
        #pragma unroll
        for (int ct = 0; ct < 9; ++ct) {
            #pragma unroll
            for (int reg = 0; reg < 4; ++reg) {
                float e = __expf(sc[ct][reg] - mx[reg]);
                sc[ct][reg] = e;
                Zs[reg] += e;
            }
        }
        #pragma unroll
        for (int reg = 0; reg < 4; ++reg) {
            #pragma unroll
            for (int off = 1; off < 16; off <<= 1)
                Zs[reg] += __shfl_xor(Zs[reg], off);
        }
        float zi[4];
        #pragma unroll
        for (int reg = 0; reg < 4; ++reg) zi[reg] = 1.0f / Zs[reg];

        // write P (C-layout -> [query][key] bf16 rows, u32-packed pairs)
        #pragma unroll
        for (int ct = 0; ct < 9; ++ct) {
            #pragma unroll
            for (int reg = 0; reg < 4; ++reg) {
                float e = sc[ct][reg];
                float ep = __shfl_xor(e, 1);
                if ((ml & 1) == 0) {
                    uint32_t pw = (uint32_t)b16bits(e) | ((uint32_t)b16bits(ep) << 16);
                    PW[wv][(quad * 4 + reg) * 84 + ct * 8 + (ml >> 1)] = pw;
                }
            }
        }

        // PV: O[16 x 64] = P[16 x 160] @ V^T ; same-wave LDS is in-order
        #pragma unroll
        for (int ct4 = 0; ct4 < 4; ++ct4) {
            f32x4 acc = {0.f, 0.f, 0.f, 0.f};
            #pragma unroll
            for (int ks = 0; ks < 5; ++ks) {
                bf16x8 ap = *reinterpret_cast<const bf16x8*>(Pb + ml * 168 + ks * 32 + quad * 8);
                bf16x8 bp = *reinterpret_cast<const bf16x8*>(Vtb + (ct4 * 16 + ml) * 168 + ks * 32 + quad * 8);
                acc = __builtin_amdgcn_mfma_f32_16x16x32_bf16(ap, bp, acc, 0, 0, 0);
            }
            #pragma unroll
            for (int reg = 0; reg < 4; ++reg) {
                int q = rt * 16 + quad * 4 + reg;
                if (q < TT) {
                    size_t oidx = (((size_t)b * TT + q) * LL + l) * HIDDEN + h * HD + ct4 * 16 + ml;
                    out[oidx] = acc[reg] * zi[reg];
                }
            }
        }
    }
}

extern "C" void kernel_launch(void* const* d_in, const int* in_sizes, int n_in,
                              void* d_out, int out_size, void* d_ws, size_t ws_size,
                              hipStream_t stream)
{
    const float* tok   = (const float*)d_in[0];
    const float* lab   = (const float*)d_in[1];
    const float* tmask = (const float*)d_in[2];
    const float* lmask = (const float*)d_in[3];
    const float* Wq    = (const float*)d_in[4];
    const float* bq    = (const float*)d_in[5];
    const float* Wk    = (const float*)d_in[6];
    const float* bk    = (const float*)d_in[7];
    const float* Wv    = (const float*)d_in[8];
    const float* bv    = (const float*)d_in[9];

    // ws: bf16 Q/K/V only — 5,308,416 B (round-2 lesson: stay small).
    bf16* Qw = (bf16*)d_ws;
    bf16* Kw = Qw + (size_t)NROWS * HIDDEN;
    bf16* Vw = Kw + (size_t)NROWS * HIDDEN;

    qkv_kernel<<<dim3(T32M * T32N / 4), 256, 0, stream>>>(
        tok, lab, Wq, bq, Wk, bk, Wv, bv, Qw, Kw, Vw);
    attn_kernel<<<dim3(BB * LL * NH), 256, 0, stream>>>(
        Qw, Kw, Vw, tmask, lmask, (float*)d_out);
}

// Round 5
// 230.392 us; speedup vs baseline: 2.3129x; 1.1883x over previous
//
#include <hip/hip_runtime.h>
#include <hip/hip_bf16.h>
#include <stdint.h>

#define HIDDEN 768
#define NH 12
#define HD 64
#define BB 8
#define SS 128
#define LL 16
#define LS 8
#define TT 136            // SS + LS
#define NROWS 1152        // BB*SS + LL*LS rows of the unique-row Xcat

typedef __attribute__((ext_vector_type(8))) short bf16x8;
typedef __attribute__((ext_vector_type(4))) float f32x4;
typedef __hip_bfloat16 bf16;

__device__ inline float tof(bf16 x) { return __bfloat162float(x); }
__device__ inline uint16_t b16bits(float f) {
    bf16 h = __float2bfloat16(f);
    union { bf16 h; uint16_t u; } u; u.h = h; return u.u;
}

// ---------------------------------------------------------------------------
// QKV projection: C[1152,2304] = Xcat @ [Wq;Wk;Wv]^T + bias.
// LDS-staged GEMM: 64x128 block tile, k-step 32. A/B staged f32->bf16 once
// per block (cvt amortized across 4 waves), inner loop = ds_read_b128 + MFMA.
// LDS stride 40 bf16 = 80 B -> 16B-aligned b128 reads, worst 2-way bank
// aliasing (free per m136). Grid 18x18 = 324 blocks.
// ---------------------------------------------------------------------------
__global__ __launch_bounds__(256) void qkv_kernel(
    const float* __restrict__ tok, const float* __restrict__ lab,
    const float* __restrict__ Wq, const float* __restrict__ bq,
    const float* __restrict__ Wk, const float* __restrict__ bk,
    const float* __restrict__ Wv, const float* __restrict__ bv,
    bf16* __restrict__ Qw, bf16* __restrict__ Kw, bf16* __restrict__ Vw)
{
    __shared__ __align__(16) uint16_t As[64 * 40];    //  5120 B
    __shared__ __align__(16) uint16_t Bs[128 * 40];   // 10240 B

    int tid = threadIdx.x;
    int lane = tid & 63, wv = tid >> 6;
    int ml = lane & 15, quad = lane >> 4;
    int mt = blockIdx.x / 18, nt = blockIdx.x % 18;   // M-tile 64, N-tile 128
    int wr = wv >> 1, wc = wv & 1;                    // wave = 32x64 sub-tile

    int mat = nt / 6;                                 // 0=Q 1=K 2=V (no straddle: 768=6*128)
    int col0 = (nt % 6) * 128;
    const float* wbase = (mat == 0) ? Wq : ((mat == 1) ? Wk : Wv);
    const float* bptr  = (mat == 0) ? bq : ((mat == 1) ? bk : bv);
    bf16* obase        = (mat == 0) ? Qw : ((mat == 1) ? Kw : Vw);

    int ar0 = mt * 64;                                // row tiles: 0..15 tok, 16..17 lab
    const float* asrc = (ar0 < 1024) ? (tok + (size_t)ar0 * HIDDEN)
                                     : (lab + (size_t)(ar0 - 1024) * HIDDEN);
    const float* bsrc = wbase + (size_t)col0 * HIDDEN;

    f32x4 acc[2][4] = {};

    for (int k0 = 0; k0 < HIDDEN; k0 += 32) {
        // stage A: 64x32 f32 -> bf16 LDS (512 float4, 2/thread)
        #pragma unroll
        for (int i = 0; i < 2; ++i) {
            int gi = i * 256 + tid;
            int r = gi >> 3, kc = (gi & 7) * 4;
            float4 v = *reinterpret_cast<const float4*>(asrc + (size_t)r * HIDDEN + k0 + kc);
            ushort4 hh;
            hh.x = b16bits(v.x); hh.y = b16bits(v.y);
            hh.z = b16bits(v.z); hh.w = b16bits(v.w);
            *reinterpret_cast<ushort4*>(&As[r * 40 + kc]) = hh;
        }
        // stage B: 128x32 f32 -> bf16 LDS (1024 float4, 4/thread)
        #pragma unroll
        for (int i = 0; i < 4; ++i) {
            int gi = i * 256 + tid;
            int r = gi >> 3, kc = (gi & 7) * 4;
            float4 v = *reinterpret_cast<const float4*>(bsrc + (size_t)r * HIDDEN + k0 + kc);
            ushort4 hh;
            hh.x = b16bits(v.x); hh.y = b16bits(v.y);
            hh.z = b16bits(v.z); hh.w = b16bits(v.w);
            *reinterpret_cast<ushort4*>(&Bs[r * 40 + kc]) = hh;
        }
        __syncthreads();

        bf16x8 af[2], bfr[4];
        #pragma unroll
        for (int rt = 0; rt < 2; ++rt)
            af[rt] = *reinterpret_cast<const bf16x8*>(&As[(wr * 32 + rt * 16 + ml) * 40 + quad * 8]);
        #pragma unroll
        for (int ct = 0; ct < 4; ++ct)
            bfr[ct] = *reinterpret_cast<const bf16x8*>(&Bs[(wc * 64 + ct * 16 + ml) * 40 + quad * 8]);
        #pragma unroll
        for (int rt = 0; rt < 2; ++rt)
            #pragma unroll
            for (int ct = 0; ct < 4; ++ct)
                acc[rt][ct] = __builtin_amdgcn_mfma_f32_16x16x32_bf16(af[rt], bfr[ct], acc[rt][ct], 0, 0, 0);
        __syncthreads();
    }

    // epilogue: + bias, bf16 store (C/D: col=ml, row=quad*4+reg)
    #pragma unroll
    for (int ct = 0; ct < 4; ++ct) {
        int c = col0 + wc * 64 + ct * 16 + ml;
        float bvv = bptr[c];
        #pragma unroll
        for (int rt = 0; rt < 2; ++rt) {
            #pragma unroll
            for (int reg = 0; reg < 4; ++reg) {
                int R = mt * 64 + wr * 32 + rt * 16 + quad * 4 + reg;
                obase[(size_t)R * HIDDEN + c] = __float2bfloat16(acc[rt][ct][reg] + bvv);
            }
        }
    }
}

// ---------------------------------------------------------------------------
// MFMA attention (UNCHANGED from round 4 — control while qkv is restructured).
// One block per (b,l,h), 4 waves; K/V^T/P staged in LDS; softmax in C-layout.
// ---------------------------------------------------------------------------
__global__ __launch_bounds__(256) void attn_kernel(
    const bf16* __restrict__ Qw, const bf16* __restrict__ Kw,
    const bf16* __restrict__ Vw,
    const float* __restrict__ tmask, const float* __restrict__ lmask,
    float* __restrict__ out)
{
    __shared__ __align__(16) uint32_t KldsW[144 * 36];   // 20736 B
    __shared__ __align__(16) uint32_t VtW[64 * 84];      // 21504 B
    __shared__ __align__(16) uint32_t PW[4][16 * 84];    // 21504 B
    __shared__ float bias_s[160];                        //   640 B

    int h = blockIdx.x % NH;
    int l = (blockIdx.x / NH) % LL;
    int b = blockIdx.x / (NH * LL);
    int tid = threadIdx.x;
    int lane = tid & 63, wv = tid >> 6;
    int ml = lane & 15, quad = lane >> 4;

    for (int i = tid; i < 144 * 32; i += 256) {
        int s = i >> 5, w = i & 31;
        uint32_t val = 0;
        if (s < TT) {
            int row = (s < SS) ? (b * SS + s) : (1024 + l * LS + (s - SS));
            val = reinterpret_cast<const uint32_t*>(Kw + (size_t)row * HIDDEN + h * HD)[w];
        }
        KldsW[s * 36 + w] = val;
    }
    for (int i = tid; i < 64 * 80; i += 256) {
        int d = i & 63, s2 = i >> 6;
        int s0 = 2 * s2, s1 = s0 + 1;
        uint16_t lo = 0, hi = 0;
        if (s0 < TT) {
            int r = (s0 < SS) ? (b * SS + s0) : (1024 + l * LS + (s0 - SS));
            lo = reinterpret_cast<const uint16_t*>(Vw + (size_t)r * HIDDEN + h * HD)[d];
        }
        if (s1 < TT) {
            int r = (s1 < SS) ? (b * SS + s1) : (1024 + l * LS + (s1 - SS));
            hi = reinterpret_cast<const uint16_t*>(Vw + (size_t)r * HIDDEN + h * HD)[d];
        }
        VtW[d * 84 + s2] = (uint32_t)lo | ((uint32_t)hi << 16);
    }
    for (int i = tid; i < 160; i += 256) {
        float bv;
        if (i < SS)       bv = (1.0f - tmask[b * SS + i]) * -10000.0f;
        else if (i < TT)  bv = (1.0f - lmask[l * LS + (i - SS)]) * -10000.0f;
        else              bv = -1e30f;
        bias_s[i] = bv;
    }
    for (int i = lane; i < 16 * 12; i += 64) {
        int r = i / 12, w2 = 68 + (i - (i / 12) * 12);
        PW[wv][r * 84 + w2] = 0;
    }
    __syncthreads();

    const bf16* Klb = reinterpret_cast<const bf16*>(KldsW);
    const bf16* Vtb = reinterpret_cast<const bf16*>(VtW);
    const bf16* Pb  = reinterpret_cast<const bf16*>(PW[wv]);

    for (int rt = wv; rt < 9; rt += 4) {
        int qr = rt * 16 + ml; if (qr > TT - 1) qr = TT - 1;
        int grow = (qr < SS) ? (b * SS + qr) : (1024 + l * LS + (qr - SS));
        const bf16* qp = Qw + (size_t)grow * HIDDEN + h * HD + quad * 8;
        bf16x8 a0 = *reinterpret_cast<const bf16x8*>(qp);
        bf16x8 a1 = *reinterpret_cast<const bf16x8*>(qp + 32);

        f32x4 sc[9];
        #pragma unroll
        for (int ct = 0; ct < 9; ++ct) {
            const bf16* kp = Klb + (ct * 16 + ml) * 72 + quad * 8;
            bf16x8 b0 = *reinterpret_cast<const bf16x8*>(kp);
            bf16x8 b1 = *reinterpret_cast<const bf16x8*>(kp + 32);
            f32x4 z = {0.f, 0.f, 0.f, 0.f};
            z = __builtin_amdgcn_mfma_f32_16x16x32_bf16(a0, b0, z, 0, 0, 0);
            z = __builtin_amdgcn_mfma_f32_16x16x32_bf16(a1, b1, z, 0, 0, 0);
            sc[ct] = z;
        }

        float mx[4] = {-1e30f, -1e30f, -1e30f, -1e30f};
        #pragma unroll
        for (int ct = 0; ct < 9; ++ct) {
            float bc = bias_s[ct * 16 + ml];
            #pragma unroll
            for (int reg = 0; reg < 4; ++reg) {
                float v = sc[ct][reg] * 0.125f + bc;
                sc[ct][reg] = v;
                mx[reg] = fmaxf(mx[reg], v);
            }
        }
        #pragma unroll
        for (int reg = 0; reg < 4; ++reg) {
            #pragma unroll
            for (int off = 1; off < 16; off <<= 1)
                mx[reg] = fmaxf(mx[reg], __shfl_xor(mx[reg], off));
        }
        float Zs[4] = {0.f, 0.f, 0.f, 0.f};
        #pragma unroll
        for (int ct = 0; ct < 9; ++ct) {
            #pragma unroll
            for (int reg = 0; reg < 4; ++reg) {
                float e = __expf(sc[ct][reg] - mx[reg]);
                sc[ct][reg] = e;
                Zs[reg] += e;
            }
        }
        #pragma unroll
        for (int reg = 0; reg < 4; ++reg) {
            #pragma unroll
            for (int off = 1; off < 16; off <<= 1)
                Zs[reg] += __shfl_xor(Zs[reg], off);
        }
        float zi[4];
        #pragma unroll
        for (int reg = 0; reg < 4; ++reg) zi[reg] = 1.0f / Zs[reg];

        #pragma unroll
        for (int ct = 0; ct < 9; ++ct) {
            #pragma unroll
            for (int reg = 0; reg < 4; ++reg) {
                float e = sc[ct][reg];
                float ep = __shfl_xor(e, 1);
                if ((ml & 1) == 0) {
                    uint32_t pw = (uint32_t)b16bits(e) | ((uint32_t)b16bits(ep) << 16);
                    PW[wv][(quad * 4 + reg) * 84 + ct * 8 + (ml >> 1)] = pw;
                }
            }
        }

        #pragma unroll
        for (int ct4 = 0; ct4 < 4; ++ct4) {
            f32x4 acc = {0.f, 0.f, 0.f, 0.f};
            #pragma unroll
            for (int ks = 0; ks < 5; ++ks) {
                bf16x8 ap = *reinterpret_cast<const bf16x8*>(Pb + ml * 168 + ks * 32 + quad * 8);
                bf16x8 bp = *reinterpret_cast<const bf16x8*>(Vtb + (ct4 * 16 + ml) * 168 + ks * 32 + quad * 8);
                acc = __builtin_amdgcn_mfma_f32_16x16x32_bf16(ap, bp, acc, 0, 0, 0);
            }
            #pragma unroll
            for (int reg = 0; reg < 4; ++reg) {
                int q = rt * 16 + quad * 4 + reg;
                if (q < TT) {
                    size_t oidx = (((size_t)b * TT + q) * LL + l) * HIDDEN + h * HD + ct4 * 16 + ml;
                    out[oidx] = acc[reg] * zi[reg];
                }
            }
        }
    }
}

extern "C" void kernel_launch(void* const* d_in, const int* in_sizes, int n_in,
                              void* d_out, int out_size, void* d_ws, size_t ws_size,
                              hipStream_t stream)
{
    const float* tok   = (const float*)d_in[0];
    const float* lab   = (const float*)d_in[1];
    const float* tmask = (const float*)d_in[2];
    const float* lmask = (const float*)d_in[3];
    const float* Wq    = (const float*)d_in[4];
    const float* bq    = (const float*)d_in[5];
    const float* Wk    = (const float*)d_in[6];
    const float* bk    = (const float*)d_in[7];
    const float* Wv    = (const float*)d_in[8];
    const float* bv    = (const float*)d_in[9];

    // ws: bf16 Q/K/V only — 5,308,416 B (round-2 lesson: stay ≤ 5.31 MB).
    bf16* Qw = (bf16*)d_ws;
    bf16* Kw = Qw + (size_t)NROWS * HIDDEN;
    bf16* Vw = Kw + (size_t)NROWS * HIDDEN;

    qkv_kernel<<<dim3(18 * 18), 256, 0, stream>>>(
        tok, lab, Wq, bq, Wk, bk, Wv, bv, Qw, Kw, Vw);
    attn_kernel<<<dim3(BB * LL * NH), 256, 0, stream>>>(
        Qw, Kw, Vw, tmask, lmask, (float*)d_out);
}

// Round 6
// 149.551 us; speedup vs baseline: 3.5631x; 1.5406x over previous
//
#include <hip/hip_runtime.h>
#include <hip/hip_bf16.h>
#include <stdint.h>

#define HIDDEN 768
#define NH 12
#define HD 64
#define BB 8
#define SS 128
#define LL 16
#define LS 8
#define TT 136            // SS + LS
#define NROWS 1152        // BB*SS + LL*LS rows of the unique-row Xcat
#define BH (BB * NH)      // 96

typedef __attribute__((ext_vector_type(8))) short bf16x8;
typedef __attribute__((ext_vector_type(4))) float f32x4;
typedef __hip_bfloat16 bf16;

__device__ inline float tof(bf16 x) { return __bfloat162float(x); }
__device__ inline uint16_t b16bits(float f) {
    bf16 h = __float2bfloat16(f);
    union { bf16 h; uint16_t u; } u; u.h = h; return u.u;
}

// ---------------------------------------------------------------------------
// QKV projection (unchanged from round 5): C[1152,2304] = Xcat @ W^T + bias.
// 64x128 block tile, k-step 32, LDS-staged bf16, 8 MFMA per wave per k-step.
// ---------------------------------------------------------------------------
__global__ __launch_bounds__(256) void qkv_kernel(
    const float* __restrict__ tok, const float* __restrict__ lab,
    const float* __restrict__ Wq, const float* __restrict__ bq,
    const float* __restrict__ Wk, const float* __restrict__ bk,
    const float* __restrict__ Wv, const float* __restrict__ bv,
    bf16* __restrict__ Qw, bf16* __restrict__ Kw, bf16* __restrict__ Vw)
{
    __shared__ __align__(16) uint16_t As[64 * 40];
    __shared__ __align__(16) uint16_t Bs[128 * 40];

    int tid = threadIdx.x;
    int lane = tid & 63, wv = tid >> 6;
    int ml = lane & 15, quad = lane >> 4;
    int mt = blockIdx.x / 18, nt = blockIdx.x % 18;
    int wr = wv >> 1, wc = wv & 1;

    int mat = nt / 6;
    int col0 = (nt % 6) * 128;
    const float* wbase = (mat == 0) ? Wq : ((mat == 1) ? Wk : Wv);
    const float* bptr  = (mat == 0) ? bq : ((mat == 1) ? bk : bv);
    bf16* obase        = (mat == 0) ? Qw : ((mat == 1) ? Kw : Vw);

    int ar0 = mt * 64;
    const float* asrc = (ar0 < 1024) ? (tok + (size_t)ar0 * HIDDEN)
                                     : (lab + (size_t)(ar0 - 1024) * HIDDEN);
    const float* bsrc = wbase + (size_t)col0 * HIDDEN;

    f32x4 acc[2][4] = {};

    for (int k0 = 0; k0 < HIDDEN; k0 += 32) {
        #pragma unroll
        for (int i = 0; i < 2; ++i) {
            int gi = i * 256 + tid;
            int r = gi >> 3, kc = (gi & 7) * 4;
            float4 v = *reinterpret_cast<const float4*>(asrc + (size_t)r * HIDDEN + k0 + kc);
            ushort4 hh;
            hh.x = b16bits(v.x); hh.y = b16bits(v.y);
            hh.z = b16bits(v.z); hh.w = b16bits(v.w);
            *reinterpret_cast<ushort4*>(&As[r * 40 + kc]) = hh;
        }
        #pragma unroll
        for (int i = 0; i < 4; ++i) {
            int gi = i * 256 + tid;
            int r = gi >> 3, kc = (gi & 7) * 4;
            float4 v = *reinterpret_cast<const float4*>(bsrc + (size_t)r * HIDDEN + k0 + kc);
            ushort4 hh;
            hh.x = b16bits(v.x); hh.y = b16bits(v.y);
            hh.z = b16bits(v.z); hh.w = b16bits(v.w);
            *reinterpret_cast<ushort4*>(&Bs[r * 40 + kc]) = hh;
        }
        __syncthreads();

        bf16x8 af[2], bfr[4];
        #pragma unroll
        for (int rt = 0; rt < 2; ++rt)
            af[rt] = *reinterpret_cast<const bf16x8*>(&As[(wr * 32 + rt * 16 + ml) * 40 + quad * 8]);
        #pragma unroll
        for (int ct = 0; ct < 4; ++ct)
            bfr[ct] = *reinterpret_cast<const bf16x8*>(&Bs[(wc * 64 + ct * 16 + ml) * 40 + quad * 8]);
        #pragma unroll
        for (int rt = 0; rt < 2; ++rt)
            #pragma unroll
            for (int ct = 0; ct < 4; ++ct)
                acc[rt][ct] = __builtin_amdgcn_mfma_f32_16x16x32_bf16(af[rt], bfr[ct], acc[rt][ct], 0, 0, 0);
        __syncthreads();
    }

    #pragma unroll
    for (int ct = 0; ct < 4; ++ct) {
        int c = col0 + wc * 64 + ct * 16 + ml;
        float bvv = bptr[c];
        #pragma unroll
        for (int rt = 0; rt < 2; ++rt) {
            #pragma unroll
            for (int reg = 0; reg < 4; ++reg) {
                int R = mt * 64 + wr * 32 + rt * 16 + quad * 4 + reg;
                obase[(size_t)R * HIDDEN + c] = __float2bfloat16(acc[rt][ct][reg] + bvv);
            }
        }
    }
}

// ---------------------------------------------------------------------------
// Phase A: token-token attention, computed ONCE per (b,h) instead of 16x.
// Grid: (b,h,half) = 192 blocks; each wave owns one 16-row query tile.
// Outputs to ws: ctx_norm[bh][128][64] bf16 (= softmax(S_tt)@V_t, normalized),
// m_tt[bh][128], d_tt[bh][128] f32 for online-softmax merging in phase B.
// ---------------------------------------------------------------------------
__global__ __launch_bounds__(256) void attn_tt_kernel(
    const bf16* __restrict__ Qw, const bf16* __restrict__ Kw,
    const bf16* __restrict__ Vw, const float* __restrict__ tmask,
    bf16* __restrict__ ctx_tt, float* __restrict__ m_tt, float* __restrict__ d_tt)
{
    __shared__ __align__(16) uint32_t KldsW[128 * 36];   // 18432 B
    __shared__ __align__(16) uint32_t VtW[64 * 68];      // 17408 B (stride 136 bf16)
    __shared__ __align__(16) uint32_t PW[4][16 * 68];    // 17408 B
    __shared__ float bias_s[128];

    int bh = blockIdx.x >> 1;
    int hf = blockIdx.x & 1;
    int b = bh / NH, h = bh % NH;
    int tid = threadIdx.x;
    int lane = tid & 63, wv = tid >> 6;
    int ml = lane & 15, quad = lane >> 4;

    for (int i = tid; i < 128 * 32; i += 256) {
        int s = i >> 5, w = i & 31;
        KldsW[s * 36 + w] =
            reinterpret_cast<const uint32_t*>(Kw + (size_t)(b * SS + s) * HIDDEN + h * HD)[w];
    }
    for (int i = tid; i < 64 * 64; i += 256) {
        int d = i & 63, s2 = i >> 6;
        const uint16_t* v0 = reinterpret_cast<const uint16_t*>(Vw + (size_t)(b * SS + 2 * s2) * HIDDEN + h * HD);
        const uint16_t* v1 = reinterpret_cast<const uint16_t*>(Vw + (size_t)(b * SS + 2 * s2 + 1) * HIDDEN + h * HD);
        VtW[d * 68 + s2] = (uint32_t)v0[d] | ((uint32_t)v1[d] << 16);
    }
    for (int i = tid; i < 128; i += 256)
        bias_s[i] = (1.0f - tmask[b * SS + i]) * -10000.0f;
    __syncthreads();

    const bf16* Klb = reinterpret_cast<const bf16*>(KldsW);
    const bf16* Vtb = reinterpret_cast<const bf16*>(VtW);
    const bf16* Pb  = reinterpret_cast<const bf16*>(PW[wv]);

    int qr = hf * 64 + wv * 16 + ml;               // query row in [0,128)
    const bf16* qp = Qw + (size_t)(b * SS + qr) * HIDDEN + h * HD + quad * 8;
    bf16x8 a0 = *reinterpret_cast<const bf16x8*>(qp);
    bf16x8 a1 = *reinterpret_cast<const bf16x8*>(qp + 32);

    f32x4 sc[8];
    #pragma unroll
    for (int ct = 0; ct < 8; ++ct) {
        const bf16* kp = Klb + (ct * 16 + ml) * 72 + quad * 8;
        bf16x8 b0 = *reinterpret_cast<const bf16x8*>(kp);
        bf16x8 b1 = *reinterpret_cast<const bf16x8*>(kp + 32);
        f32x4 z = {0.f, 0.f, 0.f, 0.f};
        z = __builtin_amdgcn_mfma_f32_16x16x32_bf16(a0, b0, z, 0, 0, 0);
        z = __builtin_amdgcn_mfma_f32_16x16x32_bf16(a1, b1, z, 0, 0, 0);
        sc[ct] = z;
    }

    float mx[4] = {-1e30f, -1e30f, -1e30f, -1e30f};
    #pragma unroll
    for (int ct = 0; ct < 8; ++ct) {
        float bc = bias_s[ct * 16 + ml];
        #pragma unroll
        for (int reg = 0; reg < 4; ++reg) {
            float v = sc[ct][reg] * 0.125f + bc;
            sc[ct][reg] = v;
            mx[reg] = fmaxf(mx[reg], v);
        }
    }
    #pragma unroll
    for (int reg = 0; reg < 4; ++reg)
        #pragma unroll
        for (int off = 1; off < 16; off <<= 1)
            mx[reg] = fmaxf(mx[reg], __shfl_xor(mx[reg], off));

    float Zs[4] = {0.f, 0.f, 0.f, 0.f};
    #pragma unroll
    for (int ct = 0; ct < 8; ++ct) {
        #pragma unroll
        for (int reg = 0; reg < 4; ++reg) {
            float e = __expf(sc[ct][reg] - mx[reg]);
            sc[ct][reg] = e;
            Zs[reg] += e;
        }
    }
    #pragma unroll
    for (int reg = 0; reg < 4; ++reg)
        #pragma unroll
        for (int off = 1; off < 16; off <<= 1)
            Zs[reg] += __shfl_xor(Zs[reg], off);

    // store m,d (rows live on quad*4+reg; lane ml==0 writes)
    #pragma unroll
    for (int reg = 0; reg < 4; ++reg) {
        int gr = bh * 128 + hf * 64 + wv * 16 + quad * 4 + reg;
        if (ml == 0) { m_tt[gr] = mx[reg]; d_tt[gr] = Zs[reg]; }
    }

    // P pack (C-layout -> row-major bf16, u32 pairs)
    #pragma unroll
    for (int ct = 0; ct < 8; ++ct) {
        #pragma unroll
        for (int reg = 0; reg < 4; ++reg) {
            float e = sc[ct][reg];
            float ep = __shfl_xor(e, 1);
            if ((ml & 1) == 0)
                PW[wv][(quad * 4 + reg) * 68 + ct * 8 + (ml >> 1)] =
                    (uint32_t)b16bits(e) | ((uint32_t)b16bits(ep) << 16);
        }
    }

    float rZ[4];
    #pragma unroll
    for (int reg = 0; reg < 4; ++reg) rZ[reg] = 1.0f / Zs[reg];

    #pragma unroll
    for (int ct4 = 0; ct4 < 4; ++ct4) {
        f32x4 acc = {0.f, 0.f, 0.f, 0.f};
        #pragma unroll
        for (int ks = 0; ks < 4; ++ks) {
            bf16x8 ap = *reinterpret_cast<const bf16x8*>(Pb + ml * 136 + ks * 32 + quad * 8);
            bf16x8 bp = *reinterpret_cast<const bf16x8*>(Vtb + (ct4 * 16 + ml) * 136 + ks * 32 + quad * 8);
            acc = __builtin_amdgcn_mfma_f32_16x16x32_bf16(ap, bp, acc, 0, 0, 0);
        }
        #pragma unroll
        for (int reg = 0; reg < 4; ++reg) {
            int gr = bh * 128 + hf * 64 + wv * 16 + quad * 4 + reg;
            ctx_tt[(size_t)gr * 64 + ct4 * 16 + ml] = __float2bfloat16(acc[reg] * rZ[reg]);
        }
    }
}

// ---------------------------------------------------------------------------
// Phase B: per (b,h,label-pair) = 768 blocks. Token-query rows: tiny 16x16
// pair-score MFMA + online-softmax merge with phase-A (m,d,ctx). Label-query
// rows (wave 3): full 144-key softmax with cross-label masking. Writes the
// entire f32 output.
// ---------------------------------------------------------------------------
__global__ __launch_bounds__(256) void attn_merge_kernel(
    const bf16* __restrict__ Qw, const bf16* __restrict__ Kw,
    const bf16* __restrict__ Vw,
    const bf16* __restrict__ ctx_tt, const float* __restrict__ m_tt,
    const float* __restrict__ d_tt,
    const float* __restrict__ tmask, const float* __restrict__ lmask,
    float* __restrict__ out)
{
    __shared__ __align__(16) uint32_t VtW[64 * 84];     // 21504 B (stride 168 bf16)
    __shared__ __align__(16) uint32_t PW[4][16 * 84];   // 21504 B
    __shared__ float mtt_s[128], dtt_s[128], bias_t[128];
    __shared__ float bias_l[16];

    int p = blockIdx.x & 7;
    int h = (blockIdx.x >> 3) % NH;
    int b = blockIdx.x / (8 * NH);
    int l0 = 2 * p, l1 = l0 + 1;
    int bh = b * NH + h;
    int tid = threadIdx.x;
    int lane = tid & 63, wv = tid >> 6;
    int ml = lane & 15, quad = lane >> 4;

    // V^T: cols 0..127 tok, 128..135 l0, 136..143 l1, 144..159 zero
    for (int i = tid; i < 64 * 80; i += 256) {
        int d = i & 63, s2 = i >> 6;
        uint32_t w = 0;
        #pragma unroll
        for (int half = 0; half < 2; ++half) {
            int s = 2 * s2 + half;
            int row = -1;
            if (s < 128)      row = b * SS + s;
            else if (s < 136) row = 1024 + l0 * LS + (s - 128);
            else if (s < 144) row = 1024 + l1 * LS + (s - 136);
            uint16_t v = 0;
            if (row >= 0)
                v = reinterpret_cast<const uint16_t*>(Vw + (size_t)row * HIDDEN + h * HD)[d];
            w |= (uint32_t)v << (16 * half);
        }
        VtW[d * 84 + s2] = w;
    }
    if (tid < 128) {
        mtt_s[tid] = m_tt[bh * 128 + tid];
        dtt_s[tid] = d_tt[bh * 128 + tid];
        bias_t[tid] = (1.0f - tmask[b * SS + tid]) * -10000.0f;
    }
    if (tid < 16) {
        int labk = (tid < 8) ? (l0 * LS + tid) : (l1 * LS + tid - 8);
        bias_l[tid] = (1.0f - lmask[labk]) * -10000.0f;
    }
    // zero P pad words 72..79 (cols 144..159) for all 4 wave buffers
    for (int i = tid; i < 4 * 16 * 8; i += 256) {
        int wvb = i >> 7, rem = i & 127;
        PW[wvb][(rem >> 3) * 84 + 72 + (rem & 7)] = 0;
    }
    __syncthreads();

    const bf16* Vtb = reinterpret_cast<const bf16*>(VtW);
    const bf16* Pb  = reinterpret_cast<const bf16*>(PW[wv]);
    const bf16x8 zfrag = {0, 0, 0, 0, 0, 0, 0, 0};

    // K pair-row fragments (B operand for token tiles; reused per tile)
    int kprow = 1024 + ((ml < 8) ? (l0 * LS + ml) : (l1 * LS + ml - 8));
    const bf16* kpp = Kw + (size_t)kprow * HIDDEN + h * HD + quad * 8;
    bf16x8 kb0 = *reinterpret_cast<const bf16x8*>(kpp);
    bf16x8 kb1 = *reinterpret_cast<const bf16x8*>(kpp + 32);

    // ---- token-query tiles: 8 tiles over 4 waves ----
    for (int rt = wv; rt < 8; rt += 4) {
        int tq = rt * 16 + ml;
        const bf16* qp = Qw + (size_t)(b * SS + tq) * HIDDEN + h * HD + quad * 8;
        bf16x8 a0 = *reinterpret_cast<const bf16x8*>(qp);
        bf16x8 a1 = *reinterpret_cast<const bf16x8*>(qp + 32);

        f32x4 z = {0.f, 0.f, 0.f, 0.f};
        z = __builtin_amdgcn_mfma_f32_16x16x32_bf16(a0, kb0, z, 0, 0, 0);
        z = __builtin_amdgcn_mfma_f32_16x16x32_bf16(a1, kb1, z, 0, 0, 0);

        float w0r[4], i0r[4], w1r[4], i1r[4];
        #pragma unroll
        for (int reg = 0; reg < 4; ++reg) {
            int grow = rt * 16 + quad * 4 + reg;
            float s = z[reg] * 0.125f + bias_l[ml];
            float m = s;
            m = fmaxf(m, __shfl_xor(m, 1));
            m = fmaxf(m, __shfl_xor(m, 2));
            m = fmaxf(m, __shfl_xor(m, 4));
            float mtt = mtt_s[grow], dtt = dtt_s[grow];
            float m_new = fmaxf(mtt, m);
            float e = __expf(s - m_new);
            float dh = e;
            dh += __shfl_xor(dh, 1);
            dh += __shfl_xor(dh, 2);
            dh += __shfl_xor(dh, 4);
            float alpha = __expf(mtt - m_new);
            float w = alpha * dtt;                 // un-normalizer for ctx_norm
            float inv = 1.0f / (w + dh);
            w0r[reg] = __shfl(w,   (lane & 48));
            i0r[reg] = __shfl(inv, (lane & 48));
            w1r[reg] = __shfl(w,   (lane & 48) | 8);
            i1r[reg] = __shfl(inv, (lane & 48) | 8);
            // P pack: row grow-local, 16 cols
            float ep = __shfl_xor(e, 1);
            if ((ml & 1) == 0)
                PW[wv][(quad * 4 + reg) * 84 + (ml >> 1)] =
                    (uint32_t)b16bits(e) | ((uint32_t)b16bits(ep) << 16);
        }

        // masked PV passes (same-wave LDS in-order): quad0 carries k=0..7
        bf16x8 aP0 = (quad == 0) ? *reinterpret_cast<const bf16x8*>(Pb + ml * 168)     : zfrag;
        bf16x8 aP1 = (quad == 0) ? *reinterpret_cast<const bf16x8*>(Pb + ml * 168 + 8) : zfrag;
        #pragma unroll
        for (int ct4 = 0; ct4 < 4; ++ct4) {
            const bf16* vrow = Vtb + (ct4 * 16 + ml) * 168;
            bf16x8 bV0 = (quad == 0) ? *reinterpret_cast<const bf16x8*>(vrow + 128) : zfrag;
            bf16x8 bV1 = (quad == 0) ? *reinterpret_cast<const bf16x8*>(vrow + 136) : zfrag;
            f32x4 pv0 = {0.f, 0.f, 0.f, 0.f}, pv1 = {0.f, 0.f, 0.f, 0.f};
            pv0 = __builtin_amdgcn_mfma_f32_16x16x32_bf16(aP0, bV0, pv0, 0, 0, 0);
            pv1 = __builtin_amdgcn_mfma_f32_16x16x32_bf16(aP1, bV1, pv1, 0, 0, 0);
            #pragma unroll
            for (int reg = 0; reg < 4; ++reg) {
                int grow = rt * 16 + quad * 4 + reg;
                float c = tof(ctx_tt[(size_t)(bh * 128 + grow) * 64 + ct4 * 16 + ml]);
                size_t ob = (((size_t)b * TT + grow) * LL) * HIDDEN + h * HD + ct4 * 16 + ml;
                out[ob + (size_t)l0 * HIDDEN] = (w0r[reg] * c + pv0[reg]) * i0r[reg];
                out[ob + (size_t)l1 * HIDDEN] = (w1r[reg] * c + pv1[reg]) * i1r[reg];
            }
        }
    }

    // ---- label-query tile (wave 3): 16 rows (8 per label), 144 keys ----
    if (wv == 3) {
        int qrow = 1024 + ((ml < 8) ? (l0 * LS + ml) : (l1 * LS + ml - 8));
        const bf16* qp = Qw + (size_t)qrow * HIDDEN + h * HD + quad * 8;
        bf16x8 a0 = *reinterpret_cast<const bf16x8*>(qp);
        bf16x8 a1 = *reinterpret_cast<const bf16x8*>(qp + 32);

        f32x4 sc[9];
        #pragma unroll
        for (int ct = 0; ct < 9; ++ct) {
            bf16x8 b0, b1;
            if (ct < 8) {
                const bf16* kp = Kw + (size_t)(b * SS + ct * 16 + ml) * HIDDEN + h * HD + quad * 8;
                b0 = *reinterpret_cast<const bf16x8*>(kp);
                b1 = *reinterpret_cast<const bf16x8*>(kp + 32);
            } else { b0 = kb0; b1 = kb1; }
            f32x4 zz = {0.f, 0.f, 0.f, 0.f};
            zz = __builtin_amdgcn_mfma_f32_16x16x32_bf16(a0, b0, zz, 0, 0, 0);
            zz = __builtin_amdgcn_mfma_f32_16x16x32_bf16(a1, b1, zz, 0, 0, 0);
            sc[ct] = zz;
        }

        float mx[4] = {-1e30f, -1e30f, -1e30f, -1e30f};
        #pragma unroll
        for (int ct = 0; ct < 9; ++ct) {
            #pragma unroll
            for (int reg = 0; reg < 4; ++reg) {
                int rq = quad * 4 + reg;
                float bc = (ct < 8) ? bias_t[ct * 16 + ml]
                                    : (((rq < 8) != (ml < 8)) ? -1e30f : bias_l[ml]);
                float v = sc[ct][reg] * 0.125f + bc;
                sc[ct][reg] = v;
                mx[reg] = fmaxf(mx[reg], v);
            }
        }
        #pragma unroll
        for (int reg = 0; reg < 4; ++reg)
            #pragma unroll
            for (int off = 1; off < 16; off <<= 1)
                mx[reg] = fmaxf(mx[reg], __shfl_xor(mx[reg], off));

        float Zs[4] = {0.f, 0.f, 0.f, 0.f};
        #pragma unroll
        for (int ct = 0; ct < 9; ++ct) {
            #pragma unroll
            for (int reg = 0; reg < 4; ++reg) {
                float e = __expf(sc[ct][reg] - mx[reg]);
                sc[ct][reg] = e;
                Zs[reg] += e;
            }
        }
        #pragma unroll
        for (int reg = 0; reg < 4; ++reg)
            #pragma unroll
            for (int off = 1; off < 16; off <<= 1)
                Zs[reg] += __shfl_xor(Zs[reg], off);
        float zi[4];
        #pragma unroll
        for (int reg = 0; reg < 4; ++reg) zi[reg] = 1.0f / Zs[reg];

        #pragma unroll
        for (int ct = 0; ct < 9; ++ct) {
            #pragma unroll
            for (int reg = 0; reg < 4; ++reg) {
                float e = sc[ct][reg];
                float ep = __shfl_xor(e, 1);
                if ((ml & 1) == 0)
                    PW[wv][(quad * 4 + reg) * 84 + ct * 8 + (ml >> 1)] =
                        (uint32_t)b16bits(e) | ((uint32_t)b16bits(ep) << 16);
            }
        }

        #pragma unroll
        for (int ct4 = 0; ct4 < 4; ++ct4) {
            f32x4 acc = {0.f, 0.f, 0.f, 0.f};
            #pragma unroll
            for (int ks = 0; ks < 5; ++ks) {
                bf16x8 ap = *reinterpret_cast<const bf16x8*>(Pb + ml * 168 + ks * 32 + quad * 8);
                bf16x8 bp = *reinterpret_cast<const bf16x8*>(Vtb + (ct4 * 16 + ml) * 168 + ks * 32 + quad * 8);
                acc = __builtin_amdgcn_mfma_f32_16x16x32_bf16(ap, bp, acc, 0, 0, 0);
            }
            #pragma unroll
            for (int reg = 0; reg < 4; ++reg) {
                int rq = quad * 4 + reg;
                int l = (rq < 8) ? l0 : l1;
                int t = SS + (rq & 7);
                out[(((size_t)b * TT + t) * LL + l) * HIDDEN + h * HD + ct4 * 16 + ml] =
                    acc[reg] * zi[reg];
            }
        }
    }
}

extern "C" void kernel_launch(void* const* d_in, const int* in_sizes, int n_in,
                              void* d_out, int out_size, void* d_ws, size_t ws_size,
                              hipStream_t stream)
{
    const float* tok   = (const float*)d_in[0];
    const float* lab   = (const float*)d_in[1];
    const float* tmask = (const float*)d_in[2];
    const float* lmask = (const float*)d_in[3];
    const float* Wq    = (const float*)d_in[4];
    const float* bq    = (const float*)d_in[5];
    const float* Wk    = (const float*)d_in[6];
    const float* bk    = (const float*)d_in[7];
    const float* Wv    = (const float*)d_in[8];
    const float* bv    = (const float*)d_in[9];

    // ws: Q/K/V bf16 (5,308,416 B) + ctx_tt bf16 (1,572,864 B)
    //     + m_tt/d_tt f32 (2 x 49,152 B) = 6,979,584 B total.
    bf16* Qw = (bf16*)d_ws;
    bf16* Kw = Qw + (size_t)NROWS * HIDDEN;
    bf16* Vw = Kw + (size_t)NROWS * HIDDEN;
    bf16* ctx = Vw + (size_t)NROWS * HIDDEN;
    float* m_tt = (float*)(ctx + (size_t)BH * 128 * 64);
    float* d_tt = m_tt + BH * 128;

    qkv_kernel<<<dim3(18 * 18), 256, 0, stream>>>(
        tok, lab, Wq, bq, Wk, bk, Wv, bv, Qw, Kw, Vw);
    attn_tt_kernel<<<dim3(BH * 2), 256, 0, stream>>>(
        Qw, Kw, Vw, tmask, ctx, m_tt, d_tt);
    attn_merge_kernel<<<dim3(BB * NH * 8), 256, 0, stream>>>(
        Qw, Kw, Vw, ctx, m_tt, d_tt, tmask, lmask, (float*)d_out);
}

// Round 7
// 138.163 us; speedup vs baseline: 3.8568x; 1.0824x over previous
//
#include <hip/hip_runtime.h>
#include <hip/hip_bf16.h>
#include <stdint.h>

#define HIDDEN 768
#define NH 12
#define HD 64
#define BB 8
#define SS 128
#define LL 16
#define LS 8
#define TT 136            // SS + LS
#define NROWS 1152        // BB*SS + LL*LS rows of the unique-row Xcat
#define BH (BB * NH)      // 96

typedef __attribute__((ext_vector_type(8))) short bf16x8;
typedef __attribute__((ext_vector_type(4))) float f32x4;
typedef __attribute__((ext_vector_type(16))) float f32x16;
typedef __hip_bfloat16 bf16;

__device__ inline float tof(bf16 x) { return __bfloat162float(x); }
__device__ inline uint16_t b16bits(float f) {
    bf16 h = __float2bfloat16(f);
    union { bf16 h; uint16_t u; } u; u.h = h; return u.u;
}

// ---------------------------------------------------------------------------
// QKV projection: C[1152,2304] = Xcat @ W^T + bias. 64x128 tile, k-step 32,
// DOUBLE-BUFFERED LDS + register prefetch -> one barrier per k-step, global
// loads of step k+1 in flight under ds_read+MFMA of step k.
// ---------------------------------------------------------------------------
__global__ __launch_bounds__(256) void qkv_kernel(
    const float* __restrict__ tok, const float* __restrict__ lab,
    const float* __restrict__ Wq, const float* __restrict__ bq,
    const float* __restrict__ Wk, const float* __restrict__ bk,
    const float* __restrict__ Wv, const float* __restrict__ bv,
    bf16* __restrict__ Qw, bf16* __restrict__ Kw, bf16* __restrict__ Vw)
{
    __shared__ __align__(16) uint16_t As[2][64 * 40];    // 2 x 5120 B
    __shared__ __align__(16) uint16_t Bs[2][128 * 40];   // 2 x 10240 B

    int tid = threadIdx.x;
    int lane = tid & 63, wv = tid >> 6;
    int ml = lane & 15, quad = lane >> 4;
    int mt = blockIdx.x / 18, nt = blockIdx.x % 18;
    int wr = wv >> 1, wc = wv & 1;

    int mat = nt / 6;
    int col0 = (nt % 6) * 128;
    const float* wbase = (mat == 0) ? Wq : ((mat == 1) ? Wk : Wv);
    const float* bptr  = (mat == 0) ? bq : ((mat == 1) ? bk : bv);
    bf16* obase        = (mat == 0) ? Qw : ((mat == 1) ? Kw : Vw);

    int ar0 = mt * 64;
    const float* asrc = (ar0 < 1024) ? (tok + (size_t)ar0 * HIDDEN)
                                     : (lab + (size_t)(ar0 - 1024) * HIDDEN);
    const float* bsrc = wbase + (size_t)col0 * HIDDEN;

    // per-thread staging coords (fixed across k-steps)
    int ra_r[2], ra_c[2], rb_r[4], rb_c[4];
    #pragma unroll
    for (int i = 0; i < 2; ++i) { int gi = i * 256 + tid; ra_r[i] = gi >> 3; ra_c[i] = (gi & 7) * 4; }
    #pragma unroll
    for (int i = 0; i < 4; ++i) { int gi = i * 256 + tid; rb_r[i] = gi >> 3; rb_c[i] = (gi & 7) * 4; }

    float4 ra[2], rb[4];
    #pragma unroll
    for (int i = 0; i < 2; ++i)
        ra[i] = *reinterpret_cast<const float4*>(asrc + (size_t)ra_r[i] * HIDDEN + ra_c[i]);
    #pragma unroll
    for (int i = 0; i < 4; ++i)
        rb[i] = *reinterpret_cast<const float4*>(bsrc + (size_t)rb_r[i] * HIDDEN + rb_c[i]);

    f32x4 acc[2][4] = {};
    int p = 0;

    for (int k0 = 0; k0 < HIDDEN; k0 += 32) {
        // commit prefetched regs -> LDS buffer p
        #pragma unroll
        for (int i = 0; i < 2; ++i) {
            ushort4 hh;
            hh.x = b16bits(ra[i].x); hh.y = b16bits(ra[i].y);
            hh.z = b16bits(ra[i].z); hh.w = b16bits(ra[i].w);
            *reinterpret_cast<ushort4*>(&As[p][ra_r[i] * 40 + ra_c[i]]) = hh;
        }
        #pragma unroll
        for (int i = 0; i < 4; ++i) {
            ushort4 hh;
            hh.x = b16bits(rb[i].x); hh.y = b16bits(rb[i].y);
            hh.z = b16bits(rb[i].z); hh.w = b16bits(rb[i].w);
            *reinterpret_cast<ushort4*>(&Bs[p][rb_r[i] * 40 + rb_c[i]]) = hh;
        }
        __syncthreads();

        // prefetch next k-step (in flight under ds_read + MFMA)
        if (k0 + 32 < HIDDEN) {
            #pragma unroll
            for (int i = 0; i < 2; ++i)
                ra[i] = *reinterpret_cast<const float4*>(asrc + (size_t)ra_r[i] * HIDDEN + k0 + 32 + ra_c[i]);
            #pragma unroll
            for (int i = 0; i < 4; ++i)
                rb[i] = *reinterpret_cast<const float4*>(bsrc + (size_t)rb_r[i] * HIDDEN + k0 + 32 + rb_c[i]);
        }

        bf16x8 af[2], bfr[4];
        #pragma unroll
        for (int rt = 0; rt < 2; ++rt)
            af[rt] = *reinterpret_cast<const bf16x8*>(&As[p][(wr * 32 + rt * 16 + ml) * 40 + quad * 8]);
        #pragma unroll
        for (int ct = 0; ct < 4; ++ct)
            bfr[ct] = *reinterpret_cast<const bf16x8*>(&Bs[p][(wc * 64 + ct * 16 + ml) * 40 + quad * 8]);
        #pragma unroll
        for (int rt = 0; rt < 2; ++rt)
            #pragma unroll
            for (int ct = 0; ct < 4; ++ct)
                acc[rt][ct] = __builtin_amdgcn_mfma_f32_16x16x32_bf16(af[rt], bfr[ct], acc[rt][ct], 0, 0, 0);
        p ^= 1;
    }

    #pragma unroll
    for (int ct = 0; ct < 4; ++ct) {
        int c = col0 + wc * 64 + ct * 16 + ml;
        float bvv = bptr[c];
        #pragma unroll
        for (int rt = 0; rt < 2; ++rt) {
            #pragma unroll
            for (int reg = 0; reg < 4; ++reg) {
                int R = mt * 64 + wr * 32 + rt * 16 + quad * 4 + reg;
                obase[(size_t)R * HIDDEN + c] = __float2bfloat16(acc[rt][ct][reg] + bvv);
            }
        }
    }
}

// ---------------------------------------------------------------------------
// Phase A: token-token attention once per (b,h) (unchanged from round 6).
// ---------------------------------------------------------------------------
__global__ __launch_bounds__(256) void attn_tt_kernel(
    const bf16* __restrict__ Qw, const bf16* __restrict__ Kw,
    const bf16* __restrict__ Vw, const float* __restrict__ tmask,
    bf16* __restrict__ ctx_tt, float* __restrict__ m_tt, float* __restrict__ d_tt)
{
    __shared__ __align__(16) uint32_t KldsW[128 * 36];
    __shared__ __align__(16) uint32_t VtW[64 * 68];
    __shared__ __align__(16) uint32_t PW[4][16 * 68];
    __shared__ float bias_s[128];

    int bh = blockIdx.x >> 1;
    int hf = blockIdx.x & 1;
    int b = bh / NH, h = bh % NH;
    int tid = threadIdx.x;
    int lane = tid & 63, wv = tid >> 6;
    int ml = lane & 15, quad = lane >> 4;

    for (int i = tid; i < 128 * 32; i += 256) {
        int s = i >> 5, w = i & 31;
        KldsW[s * 36 + w] =
            reinterpret_cast<const uint32_t*>(Kw + (size_t)(b * SS + s) * HIDDEN + h * HD)[w];
    }
    for (int i = tid; i < 64 * 64; i += 256) {
        int d = i & 63, s2 = i >> 6;
        const uint16_t* v0 = reinterpret_cast<const uint16_t*>(Vw + (size_t)(b * SS + 2 * s2) * HIDDEN + h * HD);
        const uint16_t* v1 = reinterpret_cast<const uint16_t*>(Vw + (size_t)(b * SS + 2 * s2 + 1) * HIDDEN + h * HD);
        VtW[d * 68 + s2] = (uint32_t)v0[d] | ((uint32_t)v1[d] << 16);
    }
    for (int i = tid; i < 128; i += 256)
        bias_s[i] = (1.0f - tmask[b * SS + i]) * -10000.0f;
    __syncthreads();

    const bf16* Klb = reinterpret_cast<const bf16*>(KldsW);
    const bf16* Vtb = reinterpret_cast<const bf16*>(VtW);
    const bf16* Pb  = reinterpret_cast<const bf16*>(PW[wv]);

    int qr = hf * 64 + wv * 16 + ml;
    const bf16* qp = Qw + (size_t)(b * SS + qr) * HIDDEN + h * HD + quad * 8;
    bf16x8 a0 = *reinterpret_cast<const bf16x8*>(qp);
    bf16x8 a1 = *reinterpret_cast<const bf16x8*>(qp + 32);

    f32x4 sc[8];
    #pragma unroll
    for (int ct = 0; ct < 8; ++ct) {
        const bf16* kp = Klb + (ct * 16 + ml) * 72 + quad * 8;
        bf16x8 b0 = *reinterpret_cast<const bf16x8*>(kp);
        bf16x8 b1 = *reinterpret_cast<const bf16x8*>(kp + 32);
        f32x4 z = {0.f, 0.f, 0.f, 0.f};
        z = __builtin_amdgcn_mfma_f32_16x16x32_bf16(a0, b0, z, 0, 0, 0);
        z = __builtin_amdgcn_mfma_f32_16x16x32_bf16(a1, b1, z, 0, 0, 0);
        sc[ct] = z;
    }

    float mx[4] = {-1e30f, -1e30f, -1e30f, -1e30f};
    #pragma unroll
    for (int ct = 0; ct < 8; ++ct) {
        float bc = bias_s[ct * 16 + ml];
        #pragma unroll
        for (int reg = 0; reg < 4; ++reg) {
            float v = sc[ct][reg] * 0.125f + bc;
            sc[ct][reg] = v;
            mx[reg] = fmaxf(mx[reg], v);
        }
    }
    #pragma unroll
    for (int reg = 0; reg < 4; ++reg)
        #pragma unroll
        for (int off = 1; off < 16; off <<= 1)
            mx[reg] = fmaxf(mx[reg], __shfl_xor(mx[reg], off));

    float Zs[4] = {0.f, 0.f, 0.f, 0.f};
    #pragma unroll
    for (int ct = 0; ct < 8; ++ct) {
        #pragma unroll
        for (int reg = 0; reg < 4; ++reg) {
            float e = __expf(sc[ct][reg] - mx[reg]);
            sc[ct][reg] = e;
            Zs[reg] += e;
        }
    }
    #pragma unroll
    for (int reg = 0; reg < 4; ++reg)
        #pragma unroll
        for (int off = 1; off < 16; off <<= 1)
            Zs[reg] += __shfl_xor(Zs[reg], off);

    #pragma unroll
    for (int reg = 0; reg < 4; ++reg) {
        int gr = bh * 128 + hf * 64 + wv * 16 + quad * 4 + reg;
        if (ml == 0) { m_tt[gr] = mx[reg]; d_tt[gr] = Zs[reg]; }
    }

    #pragma unroll
    for (int ct = 0; ct < 8; ++ct) {
        #pragma unroll
        for (int reg = 0; reg < 4; ++reg) {
            float e = sc[ct][reg];
            float ep = __shfl_xor(e, 1);
            if ((ml & 1) == 0)
                PW[wv][(quad * 4 + reg) * 68 + ct * 8 + (ml >> 1)] =
                    (uint32_t)b16bits(e) | ((uint32_t)b16bits(ep) << 16);
        }
    }

    float rZ[4];
    #pragma unroll
    for (int reg = 0; reg < 4; ++reg) rZ[reg] = 1.0f / Zs[reg];

    #pragma unroll
    for (int ct4 = 0; ct4 < 4; ++ct4) {
        f32x4 acc = {0.f, 0.f, 0.f, 0.f};
        #pragma unroll
        for (int ks = 0; ks < 4; ++ks) {
            bf16x8 ap = *reinterpret_cast<const bf16x8*>(Pb + ml * 136 + ks * 32 + quad * 8);
            bf16x8 bp = *reinterpret_cast<const bf16x8*>(Vtb + (ct4 * 16 + ml) * 136 + ks * 32 + quad * 8);
            acc = __builtin_amdgcn_mfma_f32_16x16x32_bf16(ap, bp, acc, 0, 0, 0);
        }
        #pragma unroll
        for (int reg = 0; reg < 4; ++reg) {
            int gr = bh * 128 + hf * 64 + wv * 16 + quad * 4 + reg;
            ctx_tt[(size_t)gr * 64 + ct4 * 16 + ml] = __float2bfloat16(acc[reg] * rZ[reg]);
        }
    }
}

// ---------------------------------------------------------------------------
// Phase B: per (b,h,label-pair) = 768 blocks.
//  - waves 0..2: 8 token-query tiles (3/3/2). Scores via 2x 16x16x32 MFMA;
//    online-softmax merge; PV via 2x DENSE mfma_32x32x16 (rows = 16 tokens x
//    {l0,l1} with disjoint k-ranges selecting the label's 8 keys).
//  - wave 3: label-query tile, full 144-key softmax (round-6 structure).
// LDS ~34 KB -> 4 blocks/CU.
// ---------------------------------------------------------------------------
__global__ __launch_bounds__(256) void attn_merge_kernel(
    const bf16* __restrict__ Qw, const bf16* __restrict__ Kw,
    const bf16* __restrict__ Vw,
    const bf16* __restrict__ ctx_tt, const float* __restrict__ m_tt,
    const float* __restrict__ d_tt,
    const float* __restrict__ tmask, const float* __restrict__ lmask,
    float* __restrict__ out)
{
    __shared__ __align__(16) uint32_t VtW[64 * 84];     // 21504 B
    __shared__ __align__(16) uint32_t PWL[16 * 84];     //  5376 B (wave-3 label P)
    __shared__ __align__(16) uint32_t P2W[4][32 * 8];   //  4096 B (token P, 32rx16c)
    __shared__ float wtab[4][32], itab[4][32];          //  1024 B
    __shared__ float mtt_s[128], dtt_s[128], bias_t[128];
    __shared__ float bias_l[16];

    int p = blockIdx.x & 7;
    int h = (blockIdx.x >> 3) % NH;
    int b = blockIdx.x / (8 * NH);
    int l0 = 2 * p, l1 = l0 + 1;
    int bh = b * NH + h;
    int tid = threadIdx.x;
    int lane = tid & 63, wv = tid >> 6;
    int ml = lane & 15, quad = lane >> 4;
    int hl = lane & 31, hi = lane >> 5;   // 32x32 MFMA coords

    // V^T: cols 0..127 tok, 128..135 l0, 136..143 l1, 144..159 zero
    for (int i = tid; i < 64 * 80; i += 256) {
        int d = i & 63, s2 = i >> 6;
        uint32_t w = 0;
        #pragma unroll
        for (int half = 0; half < 2; ++half) {
            int s = 2 * s2 + half;
            int row = -1;
            if (s < 128)      row = b * SS + s;
            else if (s < 136) row = 1024 + l0 * LS + (s - 128);
            else if (s < 144) row = 1024 + l1 * LS + (s - 136);
            uint16_t v = 0;
            if (row >= 0)
                v = reinterpret_cast<const uint16_t*>(Vw + (size_t)row * HIDDEN + h * HD)[d];
            w |= (uint32_t)v << (16 * half);
        }
        VtW[d * 84 + s2] = w;
    }
    if (tid < 128) {
        mtt_s[tid] = m_tt[bh * 128 + tid];
        dtt_s[tid] = d_tt[bh * 128 + tid];
        bias_t[tid] = (1.0f - tmask[b * SS + tid]) * -10000.0f;
    }
    if (tid < 16) {
        int labk = (tid < 8) ? (l0 * LS + tid) : (l1 * LS + tid - 8);
        bias_l[tid] = (1.0f - lmask[labk]) * -10000.0f;
    }
    // zero wave-3 P pad words 72..79 (cols 144..159)
    if (tid < 128)
        PWL[(tid >> 3) * 84 + 72 + (tid & 7)] = 0;
    __syncthreads();

    const bf16* Vtb = reinterpret_cast<const bf16*>(VtW);

    // K pair-row fragments (keys: ml<8 -> l0 key ml, ml>=8 -> l1 key ml-8)
    int kprow = 1024 + ((ml < 8) ? (l0 * LS + ml) : (l1 * LS + ml - 8));
    const bf16* kpp = Kw + (size_t)kprow * HIDDEN + h * HD + quad * 8;
    bf16x8 kb0 = *reinterpret_cast<const bf16x8*>(kpp);
    bf16x8 kb1 = *reinterpret_cast<const bf16x8*>(kpp + 32);

    if (wv < 3) {
        const bf16* P2b = reinterpret_cast<const bf16*>(P2W[wv]);
        for (int rt = wv; rt < 8; rt += 3) {
            int tq = rt * 16 + ml;
            const bf16* qp = Qw + (size_t)(b * SS + tq) * HIDDEN + h * HD + quad * 8;
            bf16x8 a0 = *reinterpret_cast<const bf16x8*>(qp);
            bf16x8 a1 = *reinterpret_cast<const bf16x8*>(qp + 32);

            f32x4 z = {0.f, 0.f, 0.f, 0.f};
            z = __builtin_amdgcn_mfma_f32_16x16x32_bf16(a0, kb0, z, 0, 0, 0);
            z = __builtin_amdgcn_mfma_f32_16x16x32_bf16(a1, kb1, z, 0, 0, 0);

            #pragma unroll
            for (int reg = 0; reg < 4; ++reg) {
                int trow = quad * 4 + reg;
                float s = z[reg] * 0.125f + bias_l[ml];
                float m = s;
                m = fmaxf(m, __shfl_xor(m, 1));
                m = fmaxf(m, __shfl_xor(m, 2));
                m = fmaxf(m, __shfl_xor(m, 4));
                float mtt = mtt_s[rt * 16 + trow], dtt = dtt_s[rt * 16 + trow];
                float m_new = fmaxf(mtt, m);
                float e = __expf(s - m_new);
                float dh = e;
                dh += __shfl_xor(dh, 1);
                dh += __shfl_xor(dh, 2);
                dh += __shfl_xor(dh, 4);
                float alpha = __expf(mtt - m_new);
                float w = alpha * dtt;
                float inv = 1.0f / (w + dh);
                if (ml == 0) { wtab[wv][trow] = w;      itab[wv][trow] = inv; }
                if (ml == 8) { wtab[wv][16 + trow] = w; itab[wv][16 + trow] = inv; }
                float ep = __shfl_xor(e, 1);
                if ((ml & 1) == 0) {
                    uint32_t pk = (uint32_t)b16bits(e) | ((uint32_t)b16bits(ep) << 16);
                    P2W[wv][trow * 8 + (ml >> 1)]        = (ml < 8) ? pk : 0u;
                    P2W[wv][(16 + trow) * 8 + (ml >> 1)] = (ml < 8) ? 0u : pk;
                }
            }

            // PV: A = P2[32 rows x 16 keys], B = Vt[dims][keys 128..143(+pad)]
            bf16x8 ap  = *reinterpret_cast<const bf16x8*>(P2b + hl * 16 + hi * 8);
            bf16x8 bv0 = *reinterpret_cast<const bf16x8*>(Vtb + hl * 168 + 128 + hi * 8);
            bf16x8 bv1 = *reinterpret_cast<const bf16x8*>(Vtb + (32 + hl) * 168 + 128 + hi * 8);
            f32x16 c0 = {}, c1 = {};
            c0 = __builtin_amdgcn_mfma_f32_32x32x16_bf16(ap, bv0, c0, 0, 0, 0);
            c1 = __builtin_amdgcn_mfma_f32_32x32x16_bf16(ap, bv1, c1, 0, 0, 0);

            // epilogue: rows 0..15 = l0, 16..31 = l1 share ctx per token row
            float cv0[8], cv1[8];
            #pragma unroll
            for (int reg = 0; reg < 8; ++reg) {
                int row = (reg & 3) + 8 * (reg >> 2) + 4 * hi;   // 0..15
                const bf16* cp = ctx_tt + (size_t)(bh * 128 + rt * 16 + row) * 64;
                cv0[reg] = tof(cp[hl]);
                cv1[reg] = tof(cp[32 + hl]);
            }
            #pragma unroll
            for (int reg = 0; reg < 16; ++reg) {
                int row = (reg & 3) + 8 * (reg >> 2) + 4 * hi;   // 0..31
                int trow = row & 15;
                int lsel = (row < 16) ? l0 : l1;
                float w = wtab[wv][row], inv = itab[wv][row];
                float c0v = (reg < 8) ? cv0[reg] : cv0[reg - 8];
                float c1v = (reg < 8) ? cv1[reg] : cv1[reg - 8];
                size_t ob = (((size_t)b * TT + rt * 16 + trow) * LL + lsel) * HIDDEN + h * HD;
                out[ob + hl]      = (w * c0v + c0[reg]) * inv;
                out[ob + 32 + hl] = (w * c1v + c1[reg]) * inv;
            }
        }
    } else {
        // ---- label-query tile: 16 rows (8 per label), 144 keys ----
        const bf16* Pb = reinterpret_cast<const bf16*>(PWL);
        int qrow = 1024 + ((ml < 8) ? (l0 * LS + ml) : (l1 * LS + ml - 8));
        const bf16* qp = Qw + (size_t)qrow * HIDDEN + h * HD + quad * 8;
        bf16x8 a0 = *reinterpret_cast<const bf16x8*>(qp);
        bf16x8 a1 = *reinterpret_cast<const bf16x8*>(qp + 32);

        f32x4 sc[9];
        #pragma unroll
        for (int ct = 0; ct < 9; ++ct) {
            bf16x8 b0, b1;
            if (ct < 8) {
                const bf16* kp = Kw + (size_t)(b * SS + ct * 16 + ml) * HIDDEN + h * HD + quad * 8;
                b0 = *reinterpret_cast<const bf16x8*>(kp);
                b1 = *reinterpret_cast<const bf16x8*>(kp + 32);
            } else { b0 = kb0; b1 = kb1; }
            f32x4 zz = {0.f, 0.f, 0.f, 0.f};
            zz = __builtin_amdgcn_mfma_f32_16x16x32_bf16(a0, b0, zz, 0, 0, 0);
            zz = __builtin_amdgcn_mfma_f32_16x16x32_bf16(a1, b1, zz, 0, 0, 0);
            sc[ct] = zz;
        }

        float mx[4] = {-1e30f, -1e30f, -1e30f, -1e30f};
        #pragma unroll
        for (int ct = 0; ct < 9; ++ct) {
            #pragma unroll
            for (int reg = 0; reg < 4; ++reg) {
                int rq = quad * 4 + reg;
                float bc = (ct < 8) ? bias_t[ct * 16 + ml]
                                    : (((rq < 8) != (ml < 8)) ? -1e30f : bias_l[ml]);
                float v = sc[ct][reg] * 0.125f + bc;
                sc[ct][reg] = v;
                mx[reg] = fmaxf(mx[reg], v);
            }
        }
        #pragma unroll
        for (int reg = 0; reg < 4; ++reg)
            #pragma unroll
            for (int off = 1; off < 16; off <<= 1)
                mx[reg] = fmaxf(mx[reg], __shfl_xor(mx[reg], off));

        float Zs[4] = {0.f, 0.f, 0.f, 0.f};
        #pragma unroll
        for (int ct = 0; ct < 9; ++ct) {
            #pragma unroll
            for (int reg = 0; reg < 4; ++reg) {
                float e = __expf(sc[ct][reg] - mx[reg]);
                sc[ct][reg] = e;
                Zs[reg] += e;
            }
        }
        #pragma unroll
        for (int reg = 0; reg < 4; ++reg)
            #pragma unroll
            for (int off = 1; off < 16; off <<= 1)
                Zs[reg] += __shfl_xor(Zs[reg], off);
        float zi[4];
        #pragma unroll
        for (int reg = 0; reg < 4; ++reg) zi[reg] = 1.0f / Zs[reg];

        #pragma unroll
        for (int ct = 0; ct < 9; ++ct) {
            #pragma unroll
            for (int reg = 0; reg < 4; ++reg) {
                float e = sc[ct][reg];
                float ep = __shfl_xor(e, 1);
                if ((ml & 1) == 0)
                    PWL[(quad * 4 + reg) * 84 + ct * 8 + (ml >> 1)] =
                        (uint32_t)b16bits(e) | ((uint32_t)b16bits(ep) << 16);
            }
        }

        #pragma unroll
        for (int ct4 = 0; ct4 < 4; ++ct4) {
            f32x4 acc = {0.f, 0.f, 0.f, 0.f};
            #pragma unroll
            for (int ks = 0; ks < 5; ++ks) {
                bf16x8 ap = *reinterpret_cast<const bf16x8*>(Pb + ml * 168 + ks * 32 + quad * 8);
                bf16x8 bp = *reinterpret_cast<const bf16x8*>(Vtb + (ct4 * 16 + ml) * 168 + ks * 32 + quad * 8);
                acc = __builtin_amdgcn_mfma_f32_16x16x32_bf16(ap, bp, acc, 0, 0, 0);
            }
            #pragma unroll
            for (int reg = 0; reg < 4; ++reg) {
                int rq = quad * 4 + reg;
                int l = (rq < 8) ? l0 : l1;
                int t = SS + (rq & 7);
                out[(((size_t)b * TT + t) * LL + l) * HIDDEN + h * HD + ct4 * 16 + ml] =
                    acc[reg] * zi[reg];
            }
        }
    }
}

extern "C" void kernel_launch(void* const* d_in, const int* in_sizes, int n_in,
                              void* d_out, int out_size, void* d_ws, size_t ws_size,
                              hipStream_t stream)
{
    const float* tok   = (const float*)d_in[0];
    const float* lab   = (const float*)d_in[1];
    const float* tmask = (const float*)d_in[2];
    const float* lmask = (const float*)d_in[3];
    const float* Wq    = (const float*)d_in[4];
    const float* bq    = (const float*)d_in[5];
    const float* Wk    = (const float*)d_in[6];
    const float* bk    = (const float*)d_in[7];
    const float* Wv    = (const float*)d_in[8];
    const float* bv    = (const float*)d_in[9];

    // ws: Q/K/V bf16 + ctx_tt bf16 + m_tt/d_tt f32 = 6,979,584 B.
    bf16* Qw = (bf16*)d_ws;
    bf16* Kw = Qw + (size_t)NROWS * HIDDEN;
    bf16* Vw = Kw + (size_t)NROWS * HIDDEN;
    bf16* ctx = Vw + (size_t)NROWS * HIDDEN;
    float* m_tt = (float*)(ctx + (size_t)BH * 128 * 64);
    float* d_tt = m_tt + BH * 128;

    qkv_kernel<<<dim3(18 * 18), 256, 0, stream>>>(
        tok, lab, Wq, bq, Wk, bk, Wv, bv, Qw, Kw, Vw);
    attn_tt_kernel<<<dim3(BH * 2), 256, 0, stream>>>(
        Qw, Kw, Vw, tmask, ctx, m_tt, d_tt);
    attn_merge_kernel<<<dim3(BB * NH * 8), 256, 0, stream>>>(
        Qw, Kw, Vw, ctx, m_tt, d_tt, tmask, lmask, (float*)d_out);
}

// Round 8
// 131.439 us; speedup vs baseline: 4.0541x; 1.0512x over previous
//
#include <hip/hip_runtime.h>
#include <hip/hip_bf16.h>
#include <stdint.h>

#define HIDDEN 768
#define NH 12
#define HD 64
#define BB 8
#define SS 128
#define LL 16
#define LS 8
#define TT 136            // SS + LS
#define NROWS 1152        // BB*SS + LL*LS rows of the unique-row Xcat
#define BH (BB * NH)      // 96

typedef __attribute__((ext_vector_type(8))) short bf16x8;
typedef __attribute__((ext_vector_type(4))) float f32x4;
typedef __attribute__((ext_vector_type(16))) float f32x16;
typedef __hip_bfloat16 bf16;

__device__ inline float tof(bf16 x) { return __bfloat162float(x); }
__device__ inline uint16_t b16bits(float f) {
    bf16 h = __float2bfloat16(f);
    union { bf16 h; uint16_t u; } u; u.h = h; return u.u;
}

// ---------------------------------------------------------------------------
// QKV projection: C[1152,2304] = Xcat @ W^T + bias. 64x128 tile, BK=64
// (12 k-steps, half the barrier drains of BK=32), double-buffered LDS +
// register prefetch. LDS row stride 72 bf16 (36 words: 2-way bank aliasing,
// free per m136).
// ---------------------------------------------------------------------------
__global__ __launch_bounds__(256) void qkv_kernel(
    const float* __restrict__ tok, const float* __restrict__ lab,
    const float* __restrict__ Wq, const float* __restrict__ bq,
    const float* __restrict__ Wk, const float* __restrict__ bk,
    const float* __restrict__ Wv, const float* __restrict__ bv,
    bf16* __restrict__ Qw, bf16* __restrict__ Kw, bf16* __restrict__ Vw)
{
    __shared__ __align__(16) uint16_t As[2][64 * 72];    // 2 x  9216 B
    __shared__ __align__(16) uint16_t Bs[2][128 * 72];   // 2 x 18432 B

    int tid = threadIdx.x;
    int lane = tid & 63, wv = tid >> 6;
    int ml = lane & 15, quad = lane >> 4;
    int mt = blockIdx.x / 18, nt = blockIdx.x % 18;
    int wr = wv >> 1, wc = wv & 1;

    int mat = nt / 6;
    int col0 = (nt % 6) * 128;
    const float* wbase = (mat == 0) ? Wq : ((mat == 1) ? Wk : Wv);
    const float* bptr  = (mat == 0) ? bq : ((mat == 1) ? bk : bv);
    bf16* obase        = (mat == 0) ? Qw : ((mat == 1) ? Kw : Vw);

    int ar0 = mt * 64;
    const float* asrc = (ar0 < 1024) ? (tok + (size_t)ar0 * HIDDEN)
                                     : (lab + (size_t)(ar0 - 1024) * HIDDEN);
    const float* bsrc = wbase + (size_t)col0 * HIDDEN;

    // staging coords: A = 64x64 f32 (1024 float4, 4/thread), B = 128x64 (8/thread)
    int ra_r[4], ra_c[4], rb_r[8], rb_c[8];
    #pragma unroll
    for (int i = 0; i < 4; ++i) { int gi = i * 256 + tid; ra_r[i] = gi >> 4; ra_c[i] = (gi & 15) * 4; }
    #pragma unroll
    for (int i = 0; i < 8; ++i) { int gi = i * 256 + tid; rb_r[i] = gi >> 4; rb_c[i] = (gi & 15) * 4; }

    float4 ra[4], rb[8];
    #pragma unroll
    for (int i = 0; i < 4; ++i)
        ra[i] = *reinterpret_cast<const float4*>(asrc + (size_t)ra_r[i] * HIDDEN + ra_c[i]);
    #pragma unroll
    for (int i = 0; i < 8; ++i)
        rb[i] = *reinterpret_cast<const float4*>(bsrc + (size_t)rb_r[i] * HIDDEN + rb_c[i]);

    f32x4 acc[2][4] = {};
    int p = 0;

    for (int k0 = 0; k0 < HIDDEN; k0 += 64) {
        #pragma unroll
        for (int i = 0; i < 4; ++i) {
            ushort4 hh;
            hh.x = b16bits(ra[i].x); hh.y = b16bits(ra[i].y);
            hh.z = b16bits(ra[i].z); hh.w = b16bits(ra[i].w);
            *reinterpret_cast<ushort4*>(&As[p][ra_r[i] * 72 + ra_c[i]]) = hh;
        }
        #pragma unroll
        for (int i = 0; i < 8; ++i) {
            ushort4 hh;
            hh.x = b16bits(rb[i].x); hh.y = b16bits(rb[i].y);
            hh.z = b16bits(rb[i].z); hh.w = b16bits(rb[i].w);
            *reinterpret_cast<ushort4*>(&Bs[p][rb_r[i] * 72 + rb_c[i]]) = hh;
        }
        __syncthreads();

        if (k0 + 64 < HIDDEN) {
            #pragma unroll
            for (int i = 0; i < 4; ++i)
                ra[i] = *reinterpret_cast<const float4*>(asrc + (size_t)ra_r[i] * HIDDEN + k0 + 64 + ra_c[i]);
            #pragma unroll
            for (int i = 0; i < 8; ++i)
                rb[i] = *reinterpret_cast<const float4*>(bsrc + (size_t)rb_r[i] * HIDDEN + k0 + 64 + rb_c[i]);
        }

        #pragma unroll
        for (int kh = 0; kh < 2; ++kh) {
            bf16x8 af[2], bfr[4];
            #pragma unroll
            for (int rt = 0; rt < 2; ++rt)
                af[rt] = *reinterpret_cast<const bf16x8*>(&As[p][(wr * 32 + rt * 16 + ml) * 72 + kh * 32 + quad * 8]);
            #pragma unroll
            for (int ct = 0; ct < 4; ++ct)
                bfr[ct] = *reinterpret_cast<const bf16x8*>(&Bs[p][(wc * 64 + ct * 16 + ml) * 72 + kh * 32 + quad * 8]);
            #pragma unroll
            for (int rt = 0; rt < 2; ++rt)
                #pragma unroll
                for (int ct = 0; ct < 4; ++ct)
                    acc[rt][ct] = __builtin_amdgcn_mfma_f32_16x16x32_bf16(af[rt], bfr[ct], acc[rt][ct], 0, 0, 0);
        }
        p ^= 1;
    }

    #pragma unroll
    for (int ct = 0; ct < 4; ++ct) {
        int c = col0 + wc * 64 + ct * 16 + ml;
        float bvv = bptr[c];
        #pragma unroll
        for (int rt = 0; rt < 2; ++rt) {
            #pragma unroll
            for (int reg = 0; reg < 4; ++reg) {
                int R = mt * 64 + wr * 32 + rt * 16 + quad * 4 + reg;
                obase[(size_t)R * HIDDEN + c] = __float2bfloat16(acc[rt][ct][reg] + bvv);
            }
        }
    }
}

// ---------------------------------------------------------------------------
// Phase A: token-token attention once per (b,h). V^T staged via COALESCED
// u32 row reads + packed LDS transpose writes (replaces 8192 scalar u16
// global loads). The hf==0 block also spills V^T to ws (Vt_g) so phase B can
// stage it with a straight coalesced copy instead of re-transposing 8x.
// ---------------------------------------------------------------------------
__global__ __launch_bounds__(256) void attn_tt_kernel(
    const bf16* __restrict__ Qw, const bf16* __restrict__ Kw,
    const bf16* __restrict__ Vw, const float* __restrict__ tmask,
    bf16* __restrict__ ctx_tt, float* __restrict__ m_tt, float* __restrict__ d_tt,
    uint32_t* __restrict__ Vt_g)
{
    __shared__ __align__(16) uint32_t KldsW[128 * 36];
    __shared__ __align__(16) uint32_t VtW[64 * 68];
    __shared__ __align__(16) uint32_t PW[4][16 * 68];
    __shared__ float bias_s[128];

    int bh = blockIdx.x >> 1;
    int hf = blockIdx.x & 1;
    int b = bh / NH, h = bh % NH;
    int tid = threadIdx.x;
    int lane = tid & 63, wv = tid >> 6;
    int ml = lane & 15, quad = lane >> 4;

    for (int i = tid; i < 128 * 32; i += 256) {
        int s = i >> 5, w = i & 31;
        KldsW[s * 36 + w] =
            reinterpret_cast<const uint32_t*>(Kw + (size_t)(b * SS + s) * HIDDEN + h * HD)[w];
    }
    // V^T build: thread loads V[2*s2][dw pair] + V[2*s2+1][dw pair] (coalesced
    // u32), writes packed pairs to Vt[2dw][s2] / Vt[2dw+1][s2].
    #pragma unroll
    for (int c = 0; c < 8; ++c) {
        int g = c * 256 + tid;             // 0..2047
        int s2 = g >> 5, dw = g & 31;
        const uint32_t* v0 = reinterpret_cast<const uint32_t*>(Vw + (size_t)(b * SS + 2 * s2) * HIDDEN + h * HD);
        const uint32_t* v1 = reinterpret_cast<const uint32_t*>(Vw + (size_t)(b * SS + 2 * s2 + 1) * HIDDEN + h * HD);
        uint32_t a = v0[dw], bb = v1[dw];
        VtW[(2 * dw) * 68 + s2]     = (a & 0xffffu) | ((bb & 0xffffu) << 16);
        VtW[(2 * dw + 1) * 68 + s2] = (a >> 16) | (bb & 0xffff0000u);
    }
    for (int i = tid; i < 128; i += 256)
        bias_s[i] = (1.0f - tmask[b * SS + i]) * -10000.0f;
    __syncthreads();

    // spill V^T (64x64 u32, [d][s2]) for phase B; only one block per bh
    if (hf == 0) {
        uint32_t* vg = Vt_g + (size_t)bh * 4096;
        #pragma unroll
        for (int c = 0; c < 16; ++c) {
            int g = c * 256 + tid;
            vg[g] = VtW[(g >> 6) * 68 + (g & 63)];
        }
    }

    const bf16* Klb = reinterpret_cast<const bf16*>(KldsW);
    const bf16* Vtb = reinterpret_cast<const bf16*>(VtW);
    const bf16* Pb  = reinterpret_cast<const bf16*>(PW[wv]);

    int qr = hf * 64 + wv * 16 + ml;
    const bf16* qp = Qw + (size_t)(b * SS + qr) * HIDDEN + h * HD + quad * 8;
    bf16x8 a0 = *reinterpret_cast<const bf16x8*>(qp);
    bf16x8 a1 = *reinterpret_cast<const bf16x8*>(qp + 32);

    f32x4 sc[8];
    #pragma unroll
    for (int ct = 0; ct < 8; ++ct) {
        const bf16* kp = Klb + (ct * 16 + ml) * 72 + quad * 8;
        bf16x8 b0 = *reinterpret_cast<const bf16x8*>(kp);
        bf16x8 b1 = *reinterpret_cast<const bf16x8*>(kp + 32);
        f32x4 z = {0.f, 0.f, 0.f, 0.f};
        z = __builtin_amdgcn_mfma_f32_16x16x32_bf16(a0, b0, z, 0, 0, 0);
        z = __builtin_amdgcn_mfma_f32_16x16x32_bf16(a1, b1, z, 0, 0, 0);
        sc[ct] = z;
    }

    float mx[4] = {-1e30f, -1e30f, -1e30f, -1e30f};
    #pragma unroll
    for (int ct = 0; ct < 8; ++ct) {
        float bc = bias_s[ct * 16 + ml];
        #pragma unroll
        for (int reg = 0; reg < 4; ++reg) {
            float v = sc[ct][reg] * 0.125f + bc;
            sc[ct][reg] = v;
            mx[reg] = fmaxf(mx[reg], v);
        }
    }
    #pragma unroll
    for (int reg = 0; reg < 4; ++reg)
        #pragma unroll
        for (int off = 1; off < 16; off <<= 1)
            mx[reg] = fmaxf(mx[reg], __shfl_xor(mx[reg], off));

    float Zs[4] = {0.f, 0.f, 0.f, 0.f};
    #pragma unroll
    for (int ct = 0; ct < 8; ++ct) {
        #pragma unroll
        for (int reg = 0; reg < 4; ++reg) {
            float e = __expf(sc[ct][reg] - mx[reg]);
            sc[ct][reg] = e;
            Zs[reg] += e;
        }
    }
    #pragma unroll
    for (int reg = 0; reg < 4; ++reg)
        #pragma unroll
        for (int off = 1; off < 16; off <<= 1)
            Zs[reg] += __shfl_xor(Zs[reg], off);

    #pragma unroll
    for (int reg = 0; reg < 4; ++reg) {
        int gr = bh * 128 + hf * 64 + wv * 16 + quad * 4 + reg;
        if (ml == 0) { m_tt[gr] = mx[reg]; d_tt[gr] = Zs[reg]; }
    }

    #pragma unroll
    for (int ct = 0; ct < 8; ++ct) {
        #pragma unroll
        for (int reg = 0; reg < 4; ++reg) {
            float e = sc[ct][reg];
            float ep = __shfl_xor(e, 1);
            if ((ml & 1) == 0)
                PW[wv][(quad * 4 + reg) * 68 + ct * 8 + (ml >> 1)] =
                    (uint32_t)b16bits(e) | ((uint32_t)b16bits(ep) << 16);
        }
    }

    float rZ[4];
    #pragma unroll
    for (int reg = 0; reg < 4; ++reg) rZ[reg] = 1.0f / Zs[reg];

    #pragma unroll
    for (int ct4 = 0; ct4 < 4; ++ct4) {
        f32x4 acc = {0.f, 0.f, 0.f, 0.f};
        #pragma unroll
        for (int ks = 0; ks < 4; ++ks) {
            bf16x8 ap = *reinterpret_cast<const bf16x8*>(Pb + ml * 136 + ks * 32 + quad * 8);
            bf16x8 bp = *reinterpret_cast<const bf16x8*>(Vtb + (ct4 * 16 + ml) * 136 + ks * 32 + quad * 8);
            acc = __builtin_amdgcn_mfma_f32_16x16x32_bf16(ap, bp, acc, 0, 0, 0);
        }
        #pragma unroll
        for (int reg = 0; reg < 4; ++reg) {
            int gr = bh * 128 + hf * 64 + wv * 16 + quad * 4 + reg;
            ctx_tt[(size_t)gr * 64 + ct4 * 16 + ml] = __float2bfloat16(acc[reg] * rZ[reg]);
        }
    }
}

// ---------------------------------------------------------------------------
// Phase B: per (b,h,label-pair) = 768 blocks. Token V^T staged by a straight
// coalesced copy from Vt_g (built once by phase A); only the 16 label cols
// are transposed here (1K scalar loads vs the old 10K).
// ---------------------------------------------------------------------------
__global__ __launch_bounds__(256) void attn_merge_kernel(
    const bf16* __restrict__ Qw, const bf16* __restrict__ Kw,
    const bf16* __restrict__ Vw, const uint32_t* __restrict__ Vt_g,
    const bf16* __restrict__ ctx_tt, const float* __restrict__ m_tt,
    const float* __restrict__ d_tt,
    const float* __restrict__ tmask, const float* __restrict__ lmask,
    float* __restrict__ out)
{
    __shared__ __align__(16) uint32_t VtW[64 * 84];     // 21504 B
    __shared__ __align__(16) uint32_t PWL[16 * 84];     //  5376 B (wave-3 label P)
    __shared__ __align__(16) uint32_t P2W[4][32 * 8];   //  4096 B (token P, 32rx16c)
    __shared__ float wtab[4][32], itab[4][32];
    __shared__ float mtt_s[128], dtt_s[128], bias_t[128];
    __shared__ float bias_l[16];

    int p = blockIdx.x & 7;
    int h = (blockIdx.x >> 3) % NH;
    int b = blockIdx.x / (8 * NH);
    int l0 = 2 * p, l1 = l0 + 1;
    int bh = b * NH + h;
    int tid = threadIdx.x;
    int lane = tid & 63, wv = tid >> 6;
    int ml = lane & 15, quad = lane >> 4;
    int hl = lane & 31, hi = lane >> 5;

    // token cols 0..127: coalesced copy from Vt_g (L2-hot)
    {
        const uint32_t* vg = Vt_g + (size_t)bh * 4096;
        #pragma unroll
        for (int c = 0; c < 16; ++c) {
            int g = c * 256 + tid;
            VtW[(g >> 6) * 84 + (g & 63)] = vg[g];
        }
    }
    // label cols 128..143 (s2 64..71): small transposed build; pad 144..159 zero
    for (int g = tid; g < 512; g += 256) {
        int d = g >> 3, jj = g & 7;
        int s0 = 128 + 2 * jj, s1 = s0 + 1;
        int r0 = (s0 < 136) ? (1024 + l0 * LS + (s0 - 128)) : (1024 + l1 * LS + (s0 - 136));
        int r1 = (s1 < 136) ? (1024 + l0 * LS + (s1 - 128)) : (1024 + l1 * LS + (s1 - 136));
        uint16_t lo = reinterpret_cast<const uint16_t*>(Vw + (size_t)r0 * HIDDEN + h * HD)[d];
        uint16_t hi2 = reinterpret_cast<const uint16_t*>(Vw + (size_t)r1 * HIDDEN + h * HD)[d];
        VtW[d * 84 + 64 + jj] = (uint32_t)lo | ((uint32_t)hi2 << 16);
    }
    for (int g = tid; g < 512; g += 256)
        VtW[(g >> 3) * 84 + 72 + (g & 7)] = 0;

    if (tid < 128) {
        mtt_s[tid] = m_tt[bh * 128 + tid];
        dtt_s[tid] = d_tt[bh * 128 + tid];
        bias_t[tid] = (1.0f - tmask[b * SS + tid]) * -10000.0f;
    }
    if (tid < 16) {
        int labk = (tid < 8) ? (l0 * LS + tid) : (l1 * LS + tid - 8);
        bias_l[tid] = (1.0f - lmask[labk]) * -10000.0f;
    }
    if (tid < 128)
        PWL[(tid >> 3) * 84 + 72 + (tid & 7)] = 0;
    __syncthreads();

    const bf16* Vtb = reinterpret_cast<const bf16*>(VtW);

    int kprow = 1024 + ((ml < 8) ? (l0 * LS + ml) : (l1 * LS + ml - 8));
    const bf16* kpp = Kw + (size_t)kprow * HIDDEN + h * HD + quad * 8;
    bf16x8 kb0 = *reinterpret_cast<const bf16x8*>(kpp);
    bf16x8 kb1 = *reinterpret_cast<const bf16x8*>(kpp + 32);

    if (wv < 3) {
        const bf16* P2b = reinterpret_cast<const bf16*>(P2W[wv]);
        for (int rt = wv; rt < 8; rt += 3) {
            int tq = rt * 16 + ml;
            const bf16* qp = Qw + (size_t)(b * SS + tq) * HIDDEN + h * HD + quad * 8;
            bf16x8 a0 = *reinterpret_cast<const bf16x8*>(qp);
            bf16x8 a1 = *reinterpret_cast<const bf16x8*>(qp + 32);

            f32x4 z = {0.f, 0.f, 0.f, 0.f};
            z = __builtin_amdgcn_mfma_f32_16x16x32_bf16(a0, kb0, z, 0, 0, 0);
            z = __builtin_amdgcn_mfma_f32_16x16x32_bf16(a1, kb1, z, 0, 0, 0);

            #pragma unroll
            for (int reg = 0; reg < 4; ++reg) {
                int trow = quad * 4 + reg;
                float s = z[reg] * 0.125f + bias_l[ml];
                float m = s;
                m = fmaxf(m, __shfl_xor(m, 1));
                m = fmaxf(m, __shfl_xor(m, 2));
                m = fmaxf(m, __shfl_xor(m, 4));
                float mtt = mtt_s[rt * 16 + trow], dtt = dtt_s[rt * 16 + trow];
                float m_new = fmaxf(mtt, m);
                float e = __expf(s - m_new);
                float dh = e;
                dh += __shfl_xor(dh, 1);
                dh += __shfl_xor(dh, 2);
                dh += __shfl_xor(dh, 4);
                float alpha = __expf(mtt - m_new);
                float w = alpha * dtt;
                float inv = 1.0f / (w + dh);
                if (ml == 0) { wtab[wv][trow] = w;      itab[wv][trow] = inv; }
                if (ml == 8) { wtab[wv][16 + trow] = w; itab[wv][16 + trow] = inv; }
                float ep = __shfl_xor(e, 1);
                if ((ml & 1) == 0) {
                    uint32_t pk = (uint32_t)b16bits(e) | ((uint32_t)b16bits(ep) << 16);
                    P2W[wv][trow * 8 + (ml >> 1)]        = (ml < 8) ? pk : 0u;
                    P2W[wv][(16 + trow) * 8 + (ml >> 1)] = (ml < 8) ? 0u : pk;
                }
            }

            bf16x8 ap  = *reinterpret_cast<const bf16x8*>(P2b + hl * 16 + hi * 8);
            bf16x8 bv0 = *reinterpret_cast<const bf16x8*>(Vtb + hl * 168 + 128 + hi * 8);
            bf16x8 bv1 = *reinterpret_cast<const bf16x8*>(Vtb + (32 + hl) * 168 + 128 + hi * 8);
            f32x16 c0 = {}, c1 = {};
            c0 = __builtin_amdgcn_mfma_f32_32x32x16_bf16(ap, bv0, c0, 0, 0, 0);
            c1 = __builtin_amdgcn_mfma_f32_32x32x16_bf16(ap, bv1, c1, 0, 0, 0);

            float cv0[8], cv1[8];
            #pragma unroll
            for (int reg = 0; reg < 8; ++reg) {
                int row = (reg & 3) + 8 * (reg >> 2) + 4 * hi;
                const bf16* cp = ctx_tt + (size_t)(bh * 128 + rt * 16 + row) * 64;
                cv0[reg] = tof(cp[hl]);
                cv1[reg] = tof(cp[32 + hl]);
            }
            #pragma unroll
            for (int reg = 0; reg < 16; ++reg) {
                int row = (reg & 3) + 8 * (reg >> 2) + 4 * hi;
                int trow = row & 15;
                int lsel = (row < 16) ? l0 : l1;
                float w = wtab[wv][row], inv = itab[wv][row];
                float c0v = (reg < 8) ? cv0[reg] : cv0[reg - 8];
                float c1v = (reg < 8) ? cv1[reg] : cv1[reg - 8];
                size_t ob = (((size_t)b * TT + rt * 16 + trow) * LL + lsel) * HIDDEN + h * HD;
                out[ob + hl]      = (w * c0v + c0[reg]) * inv;
                out[ob + 32 + hl] = (w * c1v + c1[reg]) * inv;
            }
        }
    } else {
        const bf16* Pb = reinterpret_cast<const bf16*>(PWL);
        int qrow = 1024 + ((ml < 8) ? (l0 * LS + ml) : (l1 * LS + ml - 8));
        const bf16* qp = Qw + (size_t)qrow * HIDDEN + h * HD + quad * 8;
        bf16x8 a0 = *reinterpret_cast<const bf16x8*>(qp);
        bf16x8 a1 = *reinterpret_cast<const bf16x8*>(qp + 32);

        f32x4 sc[9];
        #pragma unroll
        for (int ct = 0; ct < 9; ++ct) {
            bf16x8 b0, b1;
            if (ct < 8) {
                const bf16* kp = Kw + (size_t)(b * SS + ct * 16 + ml) * HIDDEN + h * HD + quad * 8;
                b0 = *reinterpret_cast<const bf16x8*>(kp);
                b1 = *reinterpret_cast<const bf16x8*>(kp + 32);
            } else { b0 = kb0; b1 = kb1; }
            f32x4 zz = {0.f, 0.f, 0.f, 0.f};
            zz = __builtin_amdgcn_mfma_f32_16x16x32_bf16(a0, b0, zz, 0, 0, 0);
            zz = __builtin_amdgcn_mfma_f32_16x16x32_bf16(a1, b1, zz, 0, 0, 0);
            sc[ct] = zz;
        }

        float mx[4] = {-1e30f, -1e30f, -1e30f, -1e30f};
        #pragma unroll
        for (int ct = 0; ct < 9; ++ct) {
            #pragma unroll
            for (int reg = 0; reg < 4; ++reg) {
                int rq = quad * 4 + reg;
                float bc = (ct < 8) ? bias_t[ct * 16 + ml]
                                    : (((rq < 8) != (ml < 8)) ? -1e30f : bias_l[ml]);
                float v = sc[ct][reg] * 0.125f + bc;
                sc[ct][reg] = v;
                mx[reg] = fmaxf(mx[reg], v);
            }
        }
        #pragma unroll
        for (int reg = 0; reg < 4; ++reg)
            #pragma unroll
            for (int off = 1; off < 16; off <<= 1)
                mx[reg] = fmaxf(mx[reg], __shfl_xor(mx[reg], off));

        float Zs[4] = {0.f, 0.f, 0.f, 0.f};
        #pragma unroll
        for (int ct = 0; ct < 9; ++ct) {
            #pragma unroll
            for (int reg = 0; reg < 4; ++reg) {
                float e = __expf(sc[ct][reg] - mx[reg]);
                sc[ct][reg] = e;
                Zs[reg] += e;
            }
        }
        #pragma unroll
        for (int reg = 0; reg < 4; ++reg)
            #pragma unroll
            for (int off = 1; off < 16; off <<= 1)
                Zs[reg] += __shfl_xor(Zs[reg], off);
        float zi[4];
        #pragma unroll
        for (int reg = 0; reg < 4; ++reg) zi[reg] = 1.0f / Zs[reg];

        #pragma unroll
        for (int ct = 0; ct < 9; ++ct) {
            #pragma unroll
            for (int reg = 0; reg < 4; ++reg) {
                float e = sc[ct][reg];
                float ep = __shfl_xor(e, 1);
                if ((ml & 1) == 0)
                    PWL[(quad * 4 + reg) * 84 + ct * 8 + (ml >> 1)] =
                        (uint32_t)b16bits(e) | ((uint32_t)b16bits(ep) << 16);
            }
        }

        #pragma unroll
        for (int ct4 = 0; ct4 < 4; ++ct4) {
            f32x4 acc = {0.f, 0.f, 0.f, 0.f};
            #pragma unroll
            for (int ks = 0; ks < 5; ++ks) {
                bf16x8 ap = *reinterpret_cast<const bf16x8*>(Pb + ml * 168 + ks * 32 + quad * 8);
                bf16x8 bp = *reinterpret_cast<const bf16x8*>(Vtb + (ct4 * 16 + ml) * 168 + ks * 32 + quad * 8);
                acc = __builtin_amdgcn_mfma_f32_16x16x32_bf16(ap, bp, acc, 0, 0, 0);
            }
            #pragma unroll
            for (int reg = 0; reg < 4; ++reg) {
                int rq = quad * 4 + reg;
                int l = (rq < 8) ? l0 : l1;
                int t = SS + (rq & 7);
                out[(((size_t)b * TT + t) * LL + l) * HIDDEN + h * HD + ct4 * 16 + ml] =
                    acc[reg] * zi[reg];
            }
        }
    }
}

extern "C" void kernel_launch(void* const* d_in, const int* in_sizes, int n_in,
                              void* d_out, int out_size, void* d_ws, size_t ws_size,
                              hipStream_t stream)
{
    const float* tok   = (const float*)d_in[0];
    const float* lab   = (const float*)d_in[1];
    const float* tmask = (const float*)d_in[2];
    const float* lmask = (const float*)d_in[3];
    const float* Wq    = (const float*)d_in[4];
    const float* bq    = (const float*)d_in[5];
    const float* Wk    = (const float*)d_in[6];
    const float* bk    = (const float*)d_in[7];
    const float* Wv    = (const float*)d_in[8];
    const float* bv    = (const float*)d_in[9];

    // ws: Q/K/V bf16 (5,308,416) + ctx_tt bf16 (1,572,864) + m/d f32 (98,304)
    //     + Vt_g u32 (1,572,864) = 8,552,448 B.
    bf16* Qw = (bf16*)d_ws;
    bf16* Kw = Qw + (size_t)NROWS * HIDDEN;
    bf16* Vw = Kw + (size_t)NROWS * HIDDEN;
    bf16* ctx = Vw + (size_t)NROWS * HIDDEN;
    float* m_tt = (float*)(ctx + (size_t)BH * 128 * 64);
    float* d_tt = m_tt + BH * 128;
    uint32_t* Vt_g = (uint32_t*)(d_tt + BH * 128);

    qkv_kernel<<<dim3(18 * 18), 256, 0, stream>>>(
        tok, lab, Wq, bq, Wk, bk, Wv, bv, Qw, Kw, Vw);
    attn_tt_kernel<<<dim3(BH * 2), 256, 0, stream>>>(
        Qw, Kw, Vw, tmask, ctx, m_tt, d_tt, Vt_g);
    attn_merge_kernel<<<dim3(BB * NH * 8), 256, 0, stream>>>(
        Qw, Kw, Vw, Vt_g, ctx, m_tt, d_tt, tmask, lmask, (float*)d_out);
}